// Round 1
// baseline (2246.399 us; speedup 1.0000x reference)
//
#include <hip/hip_runtime.h>
#include <math.h>

#define HH 4
#define CC 140

// ============================ CSR build ============================
__global__ __launch_bounds__(256) void k_zero_i32(int* __restrict__ p, int n) {
  int i = blockIdx.x * 256 + threadIdx.x;
  if (i < n) p[i] = 0;
}
__global__ __launch_bounds__(256) void k_hist(const int* __restrict__ idx, int n,
                                              int* __restrict__ cnt) {
  int i = blockIdx.x * 256 + threadIdx.x;
  if (i < n) atomicAdd(&cnt[idx[i]], 1);
}
// single-block chunked Hillis-Steele exclusive scan; out has n+1 entries
__global__ __launch_bounds__(1024) void k_exscan(const int* __restrict__ in, int n,
                                                 int* __restrict__ out) {
  __shared__ int buf[1024];
  __shared__ int carry_s;
  if (threadIdx.x == 0) carry_s = 0;
  __syncthreads();
  for (int base = 0; base < n; base += 1024) {
    int i = base + (int)threadIdx.x;
    int v = (i < n) ? in[i] : 0;
    buf[threadIdx.x] = v;
    __syncthreads();
    int x = v;
    for (int off = 1; off < 1024; off <<= 1) {
      int t = (threadIdx.x >= (unsigned)off) ? buf[threadIdx.x - off] : 0;
      __syncthreads();
      x += t;
      buf[threadIdx.x] = x;
      __syncthreads();
    }
    int carry = carry_s;
    if (i < n) out[i] = carry + x - v;  // exclusive
    __syncthreads();
    if (threadIdx.x == 1023) carry_s = carry + buf[1023];
    __syncthreads();
  }
  if (threadIdx.x == 0) out[n] = carry_s;
}
__global__ __launch_bounds__(256) void k_copy_i32(const int* __restrict__ a,
                                                  int* __restrict__ b, int n) {
  int i = blockIdx.x * 256 + threadIdx.x;
  if (i < n) b[i] = a[i];
}
__global__ __launch_bounds__(256) void k_scatter_edges(const int* __restrict__ src,
                                                       const int* __restrict__ dst, int nE,
                                                       int* __restrict__ cur,
                                                       int* __restrict__ slots) {
  int e = blockIdx.x * 256 + threadIdx.x;
  if (e < nE) {
    int p = atomicAdd(&cur[dst[e]], 1);
    slots[p] = src[e];
  }
}
__global__ __launch_bounds__(256) void k_scatter_nodes(const int* __restrict__ cl, int n,
                                                       int* __restrict__ cur,
                                                       int* __restrict__ slots) {
  int i = blockIdx.x * 256 + threadIdx.x;
  if (i < n) {
    int p = atomicAdd(&cur[cl[i]], 1);
    slots[p] = i;
  }
}

// ============================ GEMM (f32, split-A for concat inputs) ============================
// C[N,M] = A[N,K] @ B[K,M] (+bias per col). A row r, col k comes from A1 if k<Ks else A2.
#define BM 64
#define BN 64
#define BKK 16
__global__ __launch_bounds__(256) void k_gemm(const float* __restrict__ A1,
                                              const float* __restrict__ A2, int Ks,
                                              const float* __restrict__ B,
                                              const float* __restrict__ bias,
                                              float* __restrict__ Cd, int N, int M, int K) {
  __shared__ float As[BKK][BM + 1];
  __shared__ float Bs[BKK][BN + 1];
  const int tid = threadIdx.x;
  const int tx = tid & 15, ty = tid >> 4;
  const int row0 = blockIdx.y * BM, col0 = blockIdx.x * BN;
  float acc[4][4] = {{0.f}};
  for (int k0 = 0; k0 < K; k0 += BKK) {
    for (int i = tid; i < BM * BKK; i += 256) {
      int r = i >> 4;
      int k = i & 15;
      int gr = row0 + r, gk = k0 + k;
      float v = 0.f;
      if (gr < N && gk < K) {
        v = (gk < Ks) ? A1[(size_t)gr * Ks + gk] : A2[(size_t)gr * (K - Ks) + (gk - Ks)];
      }
      As[k][r] = v;
    }
    for (int i = tid; i < BKK * BN; i += 256) {
      int k = i >> 6;
      int c = i & 63;
      int gk = k0 + k, gc = col0 + c;
      Bs[k][c] = (gk < K && gc < M) ? B[(size_t)gk * M + gc] : 0.f;
    }
    __syncthreads();
#pragma unroll
    for (int k = 0; k < BKK; ++k) {
      float a[4], b[4];
#pragma unroll
      for (int i = 0; i < 4; ++i) a[i] = As[k][ty * 4 + i];
#pragma unroll
      for (int j = 0; j < 4; ++j) b[j] = Bs[k][tx * 4 + j];
#pragma unroll
      for (int i = 0; i < 4; ++i)
#pragma unroll
        for (int j = 0; j < 4; ++j) acc[i][j] = fmaf(a[i], b[j], acc[i][j]);
    }
    __syncthreads();
  }
#pragma unroll
  for (int i = 0; i < 4; ++i) {
    int gr = row0 + ty * 4 + i;
    if (gr >= N) continue;
#pragma unroll
    for (int j = 0; j < 4; ++j) {
      int gc = col0 + tx * 4 + j;
      if (gc >= M) continue;
      float v = acc[i][j];
      if (bias) v += bias[gc];
      Cd[(size_t)gr * M + gc] = v;
    }
  }
}

// ============================ fused FeaSt aggregation + LN + skip + relu ============================
// wave per dst node; lane covers channels {lane, lane+64, lane+128}
__global__ __launch_bounds__(256) void k_feast_agg(
    const float* __restrict__ Ab,   // (n,4) x@u
    const float* __restrict__ Y,    // (n,4,CC) x@W
    const float* __restrict__ cv,   // (4)
    const float* __restrict__ bias, // (CC)
    const float* __restrict__ g,    // (CC) or nullptr (no LN)
    const float* __restrict__ be,   // (CC)
    const float* __restrict__ skip, // (n,CC)
    const int* __restrict__ rp, const int* __restrict__ sl,
    float* __restrict__ out, int n, int do_relu) {
  int wid = blockIdx.x * 4 + ((int)threadIdx.x >> 6);
  int lane = threadIdx.x & 63;
  if (wid >= n) return;
  const float d0 = cv[0] - Ab[wid * 4 + 0];
  const float d1 = cv[1] - Ab[wid * 4 + 1];
  const float d2 = cv[2] - Ab[wid * 4 + 2];
  const float d3 = cv[3] - Ab[wid * 4 + 3];
  const int eb = rp[wid], ee = rp[wid + 1];
  const int ch0 = lane, ch1 = lane + 64, ch2 = lane + 128;
  const bool has2 = (ch2 < CC);
  float acc0 = 0.f, acc1 = 0.f, acc2 = 0.f;
  for (int e = eb; e < ee; ++e) {
    int s = sl[e];
    const float* as = Ab + (size_t)s * 4;
    float t0 = as[0] + d0, t1 = as[1] + d1, t2 = as[2] + d2, t3 = as[3] + d3;
    float m = fmaxf(fmaxf(t0, t1), fmaxf(t2, t3));
    float q0 = __expf(t0 - m), q1 = __expf(t1 - m), q2 = __expf(t2 - m), q3 = __expf(t3 - m);
    float qi = 1.f / (q0 + q1 + q2 + q3);
    q0 *= qi; q1 *= qi; q2 *= qi; q3 *= qi;
    const float* ys = Y + (size_t)s * (HH * CC);
    acc0 += q0 * ys[ch0] + q1 * ys[CC + ch0] + q2 * ys[2 * CC + ch0] + q3 * ys[3 * CC + ch0];
    acc1 += q0 * ys[ch1] + q1 * ys[CC + ch1] + q2 * ys[2 * CC + ch1] + q3 * ys[3 * CC + ch1];
    if (has2)
      acc2 += q0 * ys[ch2] + q1 * ys[CC + ch2] + q2 * ys[2 * CC + ch2] + q3 * ys[3 * CC + ch2];
  }
  int cnt = ee - eb;
  float inv = 1.f / (float)(cnt > 1 ? cnt : 1);
  float v0 = acc0 * inv + bias[ch0];
  float v1 = acc1 * inv + bias[ch1];
  float v2 = has2 ? (acc2 * inv + bias[ch2]) : 0.f;
  if (g != nullptr) {
    float s1 = v0 + v1 + v2;
    float s2 = v0 * v0 + v1 * v1 + v2 * v2;
#pragma unroll
    for (int off = 32; off > 0; off >>= 1) {
      s1 += __shfl_xor(s1, off);
      s2 += __shfl_xor(s2, off);
    }
    float mu = s1 * (1.0f / CC);
    float var = s2 * (1.0f / CC) - mu * mu;
    float r = rsqrtf(var + 1e-5f);
    v0 = (v0 - mu) * r * g[ch0] + be[ch0];
    v1 = (v1 - mu) * r * g[ch1] + be[ch1];
    if (has2) v2 = (v2 - mu) * r * g[ch2] + be[ch2];
  }
  const float* sk = skip + (size_t)wid * CC;
  v0 += sk[ch0];
  v1 += sk[ch1];
  if (has2) v2 += sk[ch2];
  if (do_relu) {
    v0 = fmaxf(v0, 0.f);
    v1 = fmaxf(v1, 0.f);
    v2 = fmaxf(v2, 0.f);
  }
  float* o = out + (size_t)wid * CC;
  o[ch0] = v0;
  o[ch1] = v1;
  if (has2) o[ch2] = v2;
}

// conv06: Cout=1, no LN, no relu; lanes split edges
__global__ __launch_bounds__(256) void k_feast_out(
    const float* __restrict__ Ab, const float* __restrict__ Y /*(n,4)*/,
    const float* __restrict__ cv, const float* __restrict__ bias /*(1)*/,
    const float* __restrict__ skip /*(n,1)*/, const int* __restrict__ rp,
    const int* __restrict__ sl, float* __restrict__ out, int n) {
  int wid = blockIdx.x * 4 + ((int)threadIdx.x >> 6);
  int lane = threadIdx.x & 63;
  if (wid >= n) return;
  const float d0 = cv[0] - Ab[wid * 4 + 0];
  const float d1 = cv[1] - Ab[wid * 4 + 1];
  const float d2 = cv[2] - Ab[wid * 4 + 2];
  const float d3 = cv[3] - Ab[wid * 4 + 3];
  const int eb = rp[wid], ee = rp[wid + 1];
  float part = 0.f;
  for (int e = eb + lane; e < ee; e += 64) {
    int s = sl[e];
    const float* as = Ab + (size_t)s * 4;
    float t0 = as[0] + d0, t1 = as[1] + d1, t2 = as[2] + d2, t3 = as[3] + d3;
    float m = fmaxf(fmaxf(t0, t1), fmaxf(t2, t3));
    float q0 = __expf(t0 - m), q1 = __expf(t1 - m), q2 = __expf(t2 - m), q3 = __expf(t3 - m);
    float qi = 1.f / (q0 + q1 + q2 + q3);
    const float* ys = Y + (size_t)s * 4;
    part += (q0 * ys[0] + q1 * ys[1] + q2 * ys[2] + q3 * ys[3]) * qi;
  }
#pragma unroll
  for (int off = 32; off > 0; off >>= 1) part += __shfl_xor(part, off);
  if (lane == 0) {
    int cnt = ee - eb;
    out[wid] = part / (float)(cnt > 1 ? cnt : 1) + bias[0] + skip[wid];
  }
}

// ============================ pooling / unpool ============================
__global__ __launch_bounds__(256) void k_seg_mean(const float* __restrict__ in,
                                                  const int* __restrict__ rp,
                                                  const int* __restrict__ sl,
                                                  float* __restrict__ out, int nseg) {
  int wid = blockIdx.x * 4 + ((int)threadIdx.x >> 6);
  int lane = threadIdx.x & 63;
  if (wid >= nseg) return;
  int a = rp[wid], b = rp[wid + 1];
  float acc0 = 0.f, acc1 = 0.f, acc2 = 0.f;
  for (int s = a; s < b; ++s) {
    const float* p = in + (size_t)sl[s] * CC;
    acc0 += p[lane];
    acc1 += p[lane + 64];
    if (lane < CC - 128) acc2 += p[lane + 128];
  }
  int cnt = b - a;
  float inv = 1.f / (float)(cnt > 1 ? cnt : 1);
  float* o = out + (size_t)wid * CC;
  o[lane] = acc0 * inv;
  o[lane + 64] = acc1 * inv;
  if (lane < CC - 128) o[lane + 128] = acc2 * inv;
}
__global__ __launch_bounds__(256) void k_gather_rows(const float* __restrict__ src,
                                                     const int* __restrict__ map,
                                                     float* __restrict__ out, int n) {
  int idx = blockIdx.x * 256 + threadIdx.x;
  if (idx >= n * CC) return;
  int i = idx / CC, ch = idx - i * CC;
  out[idx] = src[(size_t)map[i] * CC + ch];
}

// ============================ host ============================
extern "C" void kernel_launch(void* const* d_in, const int* in_sizes, int n_in,
                              void* d_out, int out_size, void* d_ws, size_t ws_size,
                              hipStream_t stream) {
  (void)n_in; (void)out_size;
  const float* x    = (const float*)d_in[0];
  const int*   e0   = (const int*)d_in[1];
  const int*   e1   = (const int*)d_in[2];
  const int*   e2   = (const int*)d_in[3];
  const int*   cl1  = (const int*)d_in[4];
  const int*   cl2  = (const int*)d_in[5];
  const float* W01  = (const float*)d_in[9];
  const float* u01  = (const float*)d_in[10];
  const float* c01  = (const float*)d_in[11];
  const float* b01  = (const float*)d_in[12];
  const float* sW01 = (const float*)d_in[13];
  const float* sb01 = (const float*)d_in[14];
  const float* g01  = (const float*)d_in[15];
  const float* be01 = (const float*)d_in[16];
  const float* Ws   = (const float*)d_in[17];
  const float* us   = (const float*)d_in[18];
  const float* cs   = (const float*)d_in[19];
  const float* bs   = (const float*)d_in[20];
  const float* gs   = (const float*)d_in[21];
  const float* bes  = (const float*)d_in[22];
  const float* Wc   = (const float*)d_in[23];
  const float* uc   = (const float*)d_in[24];
  const float* cc   = (const float*)d_in[25];
  const float* bc   = (const float*)d_in[26];
  const float* sWc  = (const float*)d_in[27];
  const float* sbc  = (const float*)d_in[28];
  const float* gc   = (const float*)d_in[29];
  const float* bec  = (const float*)d_in[30];
  const float* Wo   = (const float*)d_in[31];
  const float* uo   = (const float*)d_in[32];
  const float* co   = (const float*)d_in[33];
  const float* bo   = (const float*)d_in[34];
  const float* sWo  = (const float*)d_in[35];
  const float* sbo  = (const float*)d_in[36];

  const int N0 = in_sizes[0] / 4;
  const int nE0 = in_sizes[1] / 2;
  const int nE1 = in_sizes[2] / 2;
  const int nE2 = in_sizes[3] / 2;
  const int N1 = 5000, N2 = 1250;  // fixed per reference

  // ---- workspace layout ----
  float* fp = (float*)d_ws;
  auto alloc_f = [&](size_t n) { float* p = fp; fp += n; return p; };
  float* Y   = alloc_f((size_t)N0 * HH * CC);
  float* Ab  = alloc_f((size_t)N0 * HH);
  float* S   = alloc_f((size_t)N0 * CC);
  float* h0A = alloc_f((size_t)N0 * CC);
  float* h0B = alloc_f((size_t)N0 * CC);
  float* h1A = alloc_f((size_t)N1 * CC);
  float* h1B = alloc_f((size_t)N1 * CC);
  float* h2A = alloc_f((size_t)N2 * CC);
  float* h2B = alloc_f((size_t)N2 * CC);
  int* ipb = (int*)fp;
  auto alloc_i = [&](size_t n) { int* p = ipb; ipb += n; return p; };
  int* rp0  = alloc_i(N0 + 1);
  int* sl0  = alloc_i(nE0);
  int* rp1  = alloc_i(N1 + 1);
  int* sl1  = alloc_i(nE1);
  int* rp2  = alloc_i(N2 + 1);
  int* sl2  = alloc_i(nE2);
  int* rpc1 = alloc_i(N1 + 1);
  int* slc1 = alloc_i(N0);
  int* rpc2 = alloc_i(N2 + 1);
  int* slc2 = alloc_i(N1);
  int* cur  = alloc_i(N0 + 1);
  if ((size_t)((char*)ipb - (char*)d_ws) > ws_size) return;  // ws too small -> visible failure

  auto cdiv = [](int a, int b) { return (a + b - 1) / b; };

  // ---- CSR builds ----
  auto build_edges = [&](const int* ei, int nE, int nN, int* rp, int* sl) {
    k_zero_i32<<<cdiv(nN, 256), 256, 0, stream>>>(cur, nN);
    k_hist<<<cdiv(nE, 256), 256, 0, stream>>>(ei + nE, nE, cur);
    k_exscan<<<1, 1024, 0, stream>>>(cur, nN, rp);
    k_copy_i32<<<cdiv(nN, 256), 256, 0, stream>>>(rp, cur, nN);
    k_scatter_edges<<<cdiv(nE, 256), 256, 0, stream>>>(ei, ei + nE, nE, cur, sl);
  };
  auto build_cl = [&](const int* cl, int nSrc, int nN, int* rp, int* sl) {
    k_zero_i32<<<cdiv(nN, 256), 256, 0, stream>>>(cur, nN);
    k_hist<<<cdiv(nSrc, 256), 256, 0, stream>>>(cl, nSrc, cur);
    k_exscan<<<1, 1024, 0, stream>>>(cur, nN, rp);
    k_copy_i32<<<cdiv(nN, 256), 256, 0, stream>>>(rp, cur, nN);
    k_scatter_nodes<<<cdiv(nSrc, 256), 256, 0, stream>>>(cl, nSrc, cur, sl);
  };
  build_edges(e0, nE0, N0, rp0, sl0);
  build_edges(e1, nE1, N1, rp1, sl1);
  build_edges(e2, nE2, N2, rp2, sl2);
  build_cl(cl1, N0, N1, rpc1, slc1);
  build_cl(cl2, N1, N2, rpc2, slc2);

  auto gemm = [&](const float* A1, const float* A2, int Ks, const float* B, const float* bias,
                  float* Cd, int N, int M, int K) {
    dim3 grid(cdiv(M, BN), cdiv(N, BM));
    k_gemm<<<grid, 256, 0, stream>>>(A1, A2, Ks, B, bias, Cd, N, M, K);
  };
  // full conv: in = [in1 | in2] (in2 may be null), out Cout=CC
  auto conv = [&](const float* in1, const float* in2, int K, int n, const int* rp, const int* sl,
                  const float* Wp, const float* up, const float* cp, const float* bp,
                  const float* gp, const float* bep, const float* sWp, const float* sbp,
                  float* outp) {
    int Ks = in2 ? K / 2 : K;
    const float* a2 = in2 ? in2 : in1;
    gemm(in1, a2, Ks, Wp, nullptr, Y, n, HH * CC, K);
    gemm(in1, a2, Ks, up, nullptr, Ab, n, HH, K);
    const float* skip;
    if (sWp) {
      gemm(in1, a2, Ks, sWp, sbp, S, n, CC, K);
      skip = S;
    } else {
      skip = in1;
    }
    k_feast_agg<<<cdiv(n, 4), 256, 0, stream>>>(Ab, Y, cp, bp, gp, bep, skip, rp, sl, outp, n, 1);
  };

  auto Wi  = [&](int i) { return Ws + (size_t)i * CC * HH * CC; };
  auto ui  = [&](int i) { return us + (size_t)i * CC * HH; };
  auto ci  = [&](int i) { return cs + (size_t)i * HH; };
  auto bi  = [&](int i) { return bs + (size_t)i * CC; };
  auto gi  = [&](int i) { return gs + (size_t)i * CC; };
  auto bei = [&](int i) { return bes + (size_t)i * CC; };
  auto Wci  = [&](int i) { return Wc + (size_t)i * 2 * CC * HH * CC; };
  auto uci  = [&](int i) { return uc + (size_t)i * 2 * CC * HH; };
  auto cci  = [&](int i) { return cc + (size_t)i * HH; };
  auto bci  = [&](int i) { return bc + (size_t)i * CC; };
  auto sWci = [&](int i) { return sWc + (size_t)i * 2 * CC * CC; };
  auto sbci = [&](int i) { return sbc + (size_t)i * CC; };
  auto gci  = [&](int i) { return gc + (size_t)i * CC; };
  auto beci = [&](int i) { return bec + (size_t)i * CC; };

  // conv01: 4 -> 140, linear skip
  conv(x, nullptr, 4, N0, rp0, sl0, W01, u01, c01, b01, g01, be01, sW01, sb01, h0A);
  // conv02 (identity skip) -> h0B == copy0
  conv(h0A, nullptr, CC, N0, rp0, sl0, Wi(0), ui(0), ci(0), bi(0), gi(0), bei(0), nullptr, nullptr, h0B);
  // pool1
  k_seg_mean<<<cdiv(N1, 4), 256, 0, stream>>>(h0B, rpc1, slc1, h1A, N1);
  // conv11, conv12 (copy1 = h1A)
  conv(h1A, nullptr, CC, N1, rp1, sl1, Wi(1), ui(1), ci(1), bi(1), gi(1), bei(1), nullptr, nullptr, h1B);
  conv(h1B, nullptr, CC, N1, rp1, sl1, Wi(2), ui(2), ci(2), bi(2), gi(2), bei(2), nullptr, nullptr, h1A);
  // pool2
  k_seg_mean<<<cdiv(N2, 4), 256, 0, stream>>>(h1A, rpc2, slc2, h2A, N2);
  // conv21, conv22
  conv(h2A, nullptr, CC, N2, rp2, sl2, Wi(3), ui(3), ci(3), bi(3), gi(3), bei(3), nullptr, nullptr, h2B);
  conv(h2B, nullptr, CC, N2, rp2, sl2, Wi(4), ui(4), ci(4), bi(4), gi(4), bei(4), nullptr, nullptr, h2A);
  // unpool2 -> h1B ; conv13 on [h1B | h1A] (copy1)
  k_gather_rows<<<cdiv(N1 * CC, 256), 256, 0, stream>>>(h2A, cl2, h1B, N1);
  conv(h1B, h1A, 2 * CC, N1, rp1, sl1, Wci(0), uci(0), cci(0), bci(0), gci(0), beci(0), sWci(0), sbci(0), h1A);
  // conv14, conv15, conv16
  conv(h1A, nullptr, CC, N1, rp1, sl1, Wi(5), ui(5), ci(5), bi(5), gi(5), bei(5), nullptr, nullptr, h1B);
  conv(h1B, nullptr, CC, N1, rp1, sl1, Wi(6), ui(6), ci(6), bi(6), gi(6), bei(6), nullptr, nullptr, h1A);
  conv(h1A, nullptr, CC, N1, rp1, sl1, Wi(7), ui(7), ci(7), bi(7), gi(7), bei(7), nullptr, nullptr, h1B);
  // unpool1 -> h0A ; conv03 on [h0A | h0B] (copy0)
  k_gather_rows<<<cdiv(N0 * CC, 256), 256, 0, stream>>>(h1B, cl1, h0A, N0);
  conv(h0A, h0B, 2 * CC, N0, rp0, sl0, Wci(1), uci(1), cci(1), bci(1), gci(1), beci(1), sWci(1), sbci(1), h0A);
  // conv04, conv05
  conv(h0A, nullptr, CC, N0, rp0, sl0, Wi(8), ui(8), ci(8), bi(8), gi(8), bei(8), nullptr, nullptr, h0B);
  conv(h0B, nullptr, CC, N0, rp0, sl0, Wi(9), ui(9), ci(9), bi(9), gi(9), bei(9), nullptr, nullptr, h0A);
  // conv06: 140 -> 1, linear skip, no LN, no relu
  gemm(h0A, h0A, CC, Wo, nullptr, Y, N0, HH, CC);
  gemm(h0A, h0A, CC, uo, nullptr, Ab, N0, HH, CC);
  gemm(h0A, h0A, CC, sWo, sbo, S, N0, 1, CC);
  k_feast_out<<<cdiv(N0, 4), 256, 0, stream>>>(Ab, Y, co, bo, S, rp0, sl0, (float*)d_out, N0);
}

// Round 3
// 1292.653 us; speedup vs baseline: 1.7378x; 1.7378x over previous
//
#include <hip/hip_runtime.h>
#include <math.h>

#define HH 4
#define CC 140
#define HALF 160   // padded K of one concat half / one plain input

typedef __attribute__((ext_vector_type(8))) short short8;
typedef __attribute__((ext_vector_type(4))) float f32x4;
typedef unsigned short u16;

__device__ inline float b2f(u16 u) {
  union { float f; unsigned u; } v; v.u = ((unsigned)u) << 16; return v.f;
}
__device__ inline u16 f2b(float x) {
  union { float f; unsigned u; } v; v.f = x;
  unsigned r = v.u + 0x7FFFu + ((v.u >> 16) & 1u);
  return (u16)(r >> 16);
}

// ============================ CSR build ============================
__global__ __launch_bounds__(256) void k_zero_i32(int* __restrict__ p, int n) {
  int i = blockIdx.x * 256 + threadIdx.x;
  if (i < n) p[i] = 0;
}
__global__ __launch_bounds__(256) void k_hist(const int* __restrict__ idx, int n,
                                              int* __restrict__ cnt) {
  int i = blockIdx.x * 256 + threadIdx.x;
  if (i < n) atomicAdd(&cnt[idx[i]], 1);
}
__global__ __launch_bounds__(1024) void k_exscan(const int* __restrict__ in, int n,
                                                 int* __restrict__ out) {
  __shared__ int buf[1024];
  __shared__ int carry_s;
  if (threadIdx.x == 0) carry_s = 0;
  __syncthreads();
  for (int base = 0; base < n; base += 1024) {
    int i = base + (int)threadIdx.x;
    int v = (i < n) ? in[i] : 0;
    buf[threadIdx.x] = v;
    __syncthreads();
    int x = v;
    for (int off = 1; off < 1024; off <<= 1) {
      int t = (threadIdx.x >= (unsigned)off) ? buf[threadIdx.x - off] : 0;
      __syncthreads();
      x += t;
      buf[threadIdx.x] = x;
      __syncthreads();
    }
    int carry = carry_s;
    if (i < n) out[i] = carry + x - v;
    __syncthreads();
    if (threadIdx.x == 1023) carry_s = carry + buf[1023];
    __syncthreads();
  }
  if (threadIdx.x == 0) out[n] = carry_s;
}
__global__ __launch_bounds__(256) void k_copy_i32(const int* __restrict__ a,
                                                  int* __restrict__ b, int n) {
  int i = blockIdx.x * 256 + threadIdx.x;
  if (i < n) b[i] = a[i];
}
__global__ __launch_bounds__(256) void k_scatter_edges(const int* __restrict__ src,
                                                       const int* __restrict__ dst, int nE,
                                                       int* __restrict__ cur,
                                                       int* __restrict__ slots) {
  int e = blockIdx.x * 256 + threadIdx.x;
  if (e < nE) {
    int p = atomicAdd(&cur[dst[e]], 1);
    slots[p] = src[e];
  }
}
__global__ __launch_bounds__(256) void k_scatter_nodes(const int* __restrict__ cl, int n,
                                                       int* __restrict__ cur,
                                                       int* __restrict__ slots) {
  int i = blockIdx.x * 256 + threadIdx.x;
  if (i < n) {
    int p = atomicAdd(&cur[cl[i]], 1);
    slots[p] = i;
  }
}

// ============================ weight pack (hi+lo planes) ============================
// Bp[col][Kpad]; col<4C: W[ksrc][(col&3)*C + (col>>2)] (head-minor); [4C,4C+4): u; [4C+4,5C+4): sW
// ksrc: kp<K1 -> kp ; kp in [HALF,HALF+K2) -> K1+(kp-HALF) ; else zero
__global__ __launch_bounds__(256) void k_pack(const float* __restrict__ W,
                                              const float* __restrict__ u,
                                              const float* __restrict__ sW,
                                              u16* __restrict__ Bph, u16* __restrict__ Bpl,
                                              int C, int K1, int K2, int Kpad, int Mld) {
  int idx = blockIdx.x * 256 + threadIdx.x;
  if (idx >= Mld * Kpad) return;
  int col = idx / Kpad, kp = idx - col * Kpad;
  int ksrc = -1;
  if (kp < K1) ksrc = kp;
  else if (kp >= HALF && kp - HALF < K2) ksrc = K1 + (kp - HALF);
  float v = 0.f;
  if (ksrc >= 0) {
    if (col < 4 * C) {
      int c = col >> 2, h = col & 3;
      v = W[(size_t)ksrc * 4 * C + h * C + c];
    } else if (col < 4 * C + 4) {
      v = u[(size_t)ksrc * 4 + (col - 4 * C)];
    } else if (sW && col < 5 * C + 4) {
      v = sW[(size_t)ksrc * C + (col - 4 * C - 4)];
    }
  }
  u16 hi = f2b(v);
  Bph[idx] = hi;
  Bpl[idx] = f2b(v - b2f(hi));
}

// x (N0,4) f32 -> hi/lo planes (N0,32) zero-padded
__global__ __launch_bounds__(256) void k_pack_x(const float* __restrict__ x,
                                                u16* __restrict__ xh, u16* __restrict__ xl,
                                                int n) {
  int idx = blockIdx.x * 256 + threadIdx.x;
  if (idx >= n * 32) return;
  int i = idx >> 5, c = idx & 31;
  float v = (c < 4) ? x[(size_t)i * 4 + c] : 0.f;
  u16 hi = f2b(v);
  xh[idx] = hi;
  xl[idx] = f2b(v - b2f(hi));
}

// ============================ split-bf16 MFMA GEMM, f32 out ============================
// C_f32[N][ldc] = (Ah+Al)[N][K] @ (Bh+Bl)^T (AlBl dropped).
// A row r: kp<HALF -> A1 planes at row (amap?amap[r]:r) ; kp>=HALF -> A2 planes at row r.
// Tile 128x64, 4 waves (2x2), BK=32, XOR-swizzled LDS.
__global__ __launch_bounds__(256) void k_gemm_mfma(
    const u16* __restrict__ A1h, const u16* __restrict__ A1l,
    const u16* __restrict__ A2h, const u16* __restrict__ A2l,
    const int* __restrict__ amap,
    const u16* __restrict__ Bph, const u16* __restrict__ Bpl,
    float* __restrict__ Cd, int N, int Kpad, int lda1, int ldc) {
  __shared__ __align__(16) u16 Ash[128 * 32];
  __shared__ __align__(16) u16 Asl[128 * 32];
  __shared__ __align__(16) u16 Bsh[64 * 32];
  __shared__ __align__(16) u16 Bsl[64 * 32];
  const int tid = threadIdx.x;
  const int row0 = blockIdx.y * 128, col0 = blockIdx.x * 64;
  const int w = tid >> 6, lane = tid & 63;
  const int wm = w >> 1, wn = w & 1;
  const int arow = lane & 15, chunk = lane >> 4;
  const int swz = chunk ^ (arow & 3);
  f32x4 acc[4][2];
#pragma unroll
  for (int i = 0; i < 4; ++i)
#pragma unroll
    for (int j = 0; j < 2; ++j) acc[i][j] = (f32x4){0.f, 0.f, 0.f, 0.f};
  const int sar = tid >> 1;        // 0..127
  const int sak = (tid & 1) * 16;  // 0 / 16
  const int sbc = tid >> 2;        // 0..63
  const int sbk = (tid & 3) * 8;
  for (int k0 = 0; k0 < Kpad; k0 += 32) {
    {
      int gr = row0 + sar;
      short8 v0h = {0,0,0,0,0,0,0,0}, v1h = v0h, v0l = v0h, v1l = v0h;
      if (gr < N) {
        int kp0 = k0 + sak;
        const u16 *bh_, *bl_;
        int rr, kk, ld;
        if (A2h && kp0 >= HALF) {
          bh_ = A2h; bl_ = A2l; rr = gr; kk = kp0 - HALF; ld = HALF;
        } else {
          bh_ = A1h; bl_ = A1l; rr = amap ? amap[gr] : gr; kk = kp0; ld = lda1;
        }
        const u16* ph = bh_ + (size_t)rr * ld + kk;
        const u16* pl = bl_ + (size_t)rr * ld + kk;
        v0h = *(const short8*)(ph);
        v1h = *(const short8*)(ph + 8);
        v0l = *(const short8*)(pl);
        v1l = *(const short8*)(pl + 8);
      }
      int c0 = sak >> 3, sw = sar & 3;
      *(short8*)(Ash + sar * 32 + ((c0 ^ sw) << 3)) = v0h;
      *(short8*)(Ash + sar * 32 + (((c0 + 1) ^ sw) << 3)) = v1h;
      *(short8*)(Asl + sar * 32 + ((c0 ^ sw) << 3)) = v0l;
      *(short8*)(Asl + sar * 32 + (((c0 + 1) ^ sw) << 3)) = v1l;
    }
    {
      int gc = col0 + sbc;
      short8 vh = *(const short8*)(Bph + (size_t)gc * Kpad + k0 + sbk);
      short8 vl = *(const short8*)(Bpl + (size_t)gc * Kpad + k0 + sbk);
      int c = sbk >> 3, sw = sbc & 3;
      *(short8*)(Bsh + sbc * 32 + ((c ^ sw) << 3)) = vh;
      *(short8*)(Bsl + sbc * 32 + ((c ^ sw) << 3)) = vl;
    }
    __syncthreads();
    short8 bh[2], bl[2], ah[4], al[4];
#pragma unroll
    for (int ni = 0; ni < 2; ++ni) {
      int col = wn * 32 + ni * 16 + arow;
      bh[ni] = *(const short8*)(Bsh + col * 32 + (swz << 3));
      bl[ni] = *(const short8*)(Bsl + col * 32 + (swz << 3));
    }
#pragma unroll
    for (int mi = 0; mi < 4; ++mi) {
      int r = wm * 64 + mi * 16 + arow;
      ah[mi] = *(const short8*)(Ash + r * 32 + (swz << 3));
      al[mi] = *(const short8*)(Asl + r * 32 + (swz << 3));
    }
#pragma unroll
    for (int mi = 0; mi < 4; ++mi)
#pragma unroll
      for (int ni = 0; ni < 2; ++ni)
        acc[mi][ni] = __builtin_amdgcn_mfma_f32_16x16x32_bf16(ah[mi], bh[ni], acc[mi][ni], 0, 0, 0);
#pragma unroll
    for (int mi = 0; mi < 4; ++mi)
#pragma unroll
      for (int ni = 0; ni < 2; ++ni)
        acc[mi][ni] = __builtin_amdgcn_mfma_f32_16x16x32_bf16(ah[mi], bl[ni], acc[mi][ni], 0, 0, 0);
#pragma unroll
    for (int mi = 0; mi < 4; ++mi)
#pragma unroll
      for (int ni = 0; ni < 2; ++ni)
        acc[mi][ni] = __builtin_amdgcn_mfma_f32_16x16x32_bf16(al[mi], bh[ni], acc[mi][ni], 0, 0, 0);
    __syncthreads();
  }
  const int crow = (lane >> 4) * 4, ccol = lane & 15;
#pragma unroll
  for (int mi = 0; mi < 4; ++mi) {
    int gr0 = row0 + wm * 64 + mi * 16 + crow;
#pragma unroll
    for (int ni = 0; ni < 2; ++ni) {
      int gc = col0 + wn * 32 + ni * 16 + ccol;
#pragma unroll
      for (int j = 0; j < 4; ++j) {
        int gr = gr0 + j;
        if (gr < N) Cd[(size_t)gr * ldc + gc] = acc[mi][ni][j];
      }
    }
  }
}

// ============================ fused FeaSt agg + LN + skip + relu (f32 G) ============================
// G row: cols c*4+h (c<140,h<4) = Y ; 560..563 = logits ; 564..703 = GEMM skip (if used)
__global__ __launch_bounds__(256) void k_agg(
    const float* __restrict__ G, int ldg,
    const float* __restrict__ cv, const float* __restrict__ bias,
    const float* __restrict__ g, const float* __restrict__ be,
    const u16* __restrict__ inH, const u16* __restrict__ inL,  // identity skip (or null)
    const float* __restrict__ sb,                               // GEMM-skip bias
    const int* __restrict__ rp, const int* __restrict__ sl,
    u16* __restrict__ outH, u16* __restrict__ outL, int n, int relu) {
  int wid = blockIdx.x * 4 + ((int)threadIdx.x >> 6);
  int lane = threadIdx.x & 63;
  if (wid >= n) return;
  const float* gw = G + (size_t)wid * ldg;
  float4 la = *(const float4*)(gw + 560);
  float d0 = cv[0] - la.x, d1 = cv[1] - la.y;
  float d2 = cv[2] - la.z, d3 = cv[3] - la.w;
  int eb = rp[wid], ee = rp[wid + 1];
  const int c0 = lane, c1 = lane + 64, c2 = lane + 128;
  const bool h2v = c2 < CC;
  float acc0 = 0.f, acc1 = 0.f, acc2 = 0.f;
  for (int e = eb; e < ee; ++e) {
    int s = sl[e];
    const float* gs = G + (size_t)s * ldg;
    float4 lg = *(const float4*)(gs + 560);
    float t0 = lg.x + d0, t1 = lg.y + d1, t2 = lg.z + d2, t3 = lg.w + d3;
    float m = fmaxf(fmaxf(t0, t1), fmaxf(t2, t3));
    float q0 = __expf(t0 - m), q1 = __expf(t1 - m), q2 = __expf(t2 - m), q3 = __expf(t3 - m);
    float qi = 1.f / (q0 + q1 + q2 + q3);
    q0 *= qi; q1 *= qi; q2 *= qi; q3 *= qi;
    float4 y0 = *(const float4*)(gs + (c0 << 2));
    acc0 += q0 * y0.x + q1 * y0.y + q2 * y0.z + q3 * y0.w;
    float4 y1 = *(const float4*)(gs + (c1 << 2));
    acc1 += q0 * y1.x + q1 * y1.y + q2 * y1.z + q3 * y1.w;
    if (h2v) {
      float4 y2 = *(const float4*)(gs + (c2 << 2));
      acc2 += q0 * y2.x + q1 * y2.y + q2 * y2.z + q3 * y2.w;
    }
  }
  int cnt = ee - eb;
  float inv = 1.f / (float)(cnt > 1 ? cnt : 1);
  float v0 = acc0 * inv + bias[c0];
  float v1 = acc1 * inv + bias[c1];
  float v2 = h2v ? acc2 * inv + bias[c2] : 0.f;
  if (g) {
    float s1 = v0 + v1 + v2;
    float s2 = v0 * v0 + v1 * v1 + v2 * v2;
#pragma unroll
    for (int off = 32; off > 0; off >>= 1) {
      s1 += __shfl_xor(s1, off);
      s2 += __shfl_xor(s2, off);
    }
    float mu = s1 * (1.0f / CC);
    float var = s2 * (1.0f / CC) - mu * mu;
    float r = rsqrtf(var + 1e-5f);
    v0 = (v0 - mu) * r * g[c0] + be[c0];
    v1 = (v1 - mu) * r * g[c1] + be[c1];
    if (h2v) v2 = (v2 - mu) * r * g[c2] + be[c2];
  }
  if (inH) {
    const u16* ih = inH + (size_t)wid * HALF;
    const u16* il = inL + (size_t)wid * HALF;
    v0 += b2f(ih[c0]) + b2f(il[c0]);
    v1 += b2f(ih[c1]) + b2f(il[c1]);
    if (h2v) v2 += b2f(ih[c2]) + b2f(il[c2]);
  } else {
    v0 += gw[564 + c0] + sb[c0];
    v1 += gw[564 + c1] + sb[c1];
    if (h2v) v2 += gw[564 + c2] + sb[c2];
  }
  if (relu) {
    v0 = fmaxf(v0, 0.f); v1 = fmaxf(v1, 0.f); v2 = fmaxf(v2, 0.f);
  }
  u16* oh = outH + (size_t)wid * HALF;
  u16* ol = outL + (size_t)wid * HALF;
  u16 h0 = f2b(v0); oh[c0] = h0; ol[c0] = f2b(v0 - b2f(h0));
  u16 h1 = f2b(v1); oh[c1] = h1; ol[c1] = f2b(v1 - b2f(h1));
  if (h2v) {
    u16 h2 = f2b(v2); oh[c2] = h2; ol[c2] = f2b(v2 - b2f(h2));
  } else if (c2 < HALF) {
    oh[c2] = 0; ol[c2] = 0;
  }
}

// conv06: G cols 0..3 = Y heads, 4..7 = logits, 8 = skip
__global__ __launch_bounds__(256) void k_out(
    const float* __restrict__ G, int ldg,
    const float* __restrict__ cv, const float* __restrict__ bo,
    const float* __restrict__ sbo, const int* __restrict__ rp,
    const int* __restrict__ sl, float* __restrict__ out, int n) {
  int wid = blockIdx.x * 4 + ((int)threadIdx.x >> 6);
  int lane = threadIdx.x & 63;
  if (wid >= n) return;
  const float* gw = G + (size_t)wid * ldg;
  float4 la = *(const float4*)(gw + 4);
  float d0 = cv[0] - la.x, d1 = cv[1] - la.y;
  float d2 = cv[2] - la.z, d3 = cv[3] - la.w;
  int eb = rp[wid], ee = rp[wid + 1];
  float part = 0.f;
  for (int e = eb + lane; e < ee; e += 64) {
    int s = sl[e];
    const float* gs = G + (size_t)s * ldg;
    float4 lg = *(const float4*)(gs + 4);
    float t0 = lg.x + d0, t1 = lg.y + d1, t2 = lg.z + d2, t3 = lg.w + d3;
    float m = fmaxf(fmaxf(t0, t1), fmaxf(t2, t3));
    float q0 = __expf(t0 - m), q1 = __expf(t1 - m), q2 = __expf(t2 - m), q3 = __expf(t3 - m);
    float qi = 1.f / (q0 + q1 + q2 + q3);
    float4 y = *(const float4*)(gs + 0);
    part += (q0 * y.x + q1 * y.y + q2 * y.z + q3 * y.w) * qi;
  }
#pragma unroll
  for (int off = 32; off > 0; off >>= 1) part += __shfl_xor(part, off);
  if (lane == 0) {
    int cnt = ee - eb;
    out[wid] = part / (float)(cnt > 1 ? cnt : 1) + bo[0] + gw[8] + sbo[0];
  }
}

// ============================ pool (split planes in/out) ============================
__global__ __launch_bounds__(256) void k_pool(const u16* __restrict__ inH,
                                              const u16* __restrict__ inL,
                                              const int* __restrict__ rp,
                                              const int* __restrict__ sl,
                                              u16* __restrict__ outH,
                                              u16* __restrict__ outL, int nseg) {
  int wid = blockIdx.x * 4 + ((int)threadIdx.x >> 6);
  int lane = threadIdx.x & 63;
  if (wid >= nseg) return;
  int a = rp[wid], b = rp[wid + 1];
  const int c0 = lane, c1 = lane + 64, c2 = lane + 128;
  const bool h2v = c2 < CC;
  float acc0 = 0.f, acc1 = 0.f, acc2 = 0.f;
  for (int s = a; s < b; ++s) {
    size_t off = (size_t)sl[s] * HALF;
    acc0 += b2f(inH[off + c0]) + b2f(inL[off + c0]);
    acc1 += b2f(inH[off + c1]) + b2f(inL[off + c1]);
    if (h2v) acc2 += b2f(inH[off + c2]) + b2f(inL[off + c2]);
  }
  int cnt = b - a;
  float inv = 1.f / (float)(cnt > 1 ? cnt : 1);
  float v0 = acc0 * inv, v1 = acc1 * inv, v2 = acc2 * inv;
  u16* oh = outH + (size_t)wid * HALF;
  u16* ol = outL + (size_t)wid * HALF;
  u16 h0 = f2b(v0); oh[c0] = h0; ol[c0] = f2b(v0 - b2f(h0));
  u16 h1 = f2b(v1); oh[c1] = h1; ol[c1] = f2b(v1 - b2f(h1));
  if (h2v) {
    u16 h2 = f2b(v2); oh[c2] = h2; ol[c2] = f2b(v2 - b2f(h2));
  } else if (c2 < HALF) {
    oh[c2] = 0; ol[c2] = 0;
  }
}

// ============================ host ============================
extern "C" void kernel_launch(void* const* d_in, const int* in_sizes, int n_in,
                              void* d_out, int out_size, void* d_ws, size_t ws_size,
                              hipStream_t stream) {
  (void)n_in; (void)out_size;
  const float* x    = (const float*)d_in[0];
  const int*   e0   = (const int*)d_in[1];
  const int*   e1   = (const int*)d_in[2];
  const int*   e2   = (const int*)d_in[3];
  const int*   cl1  = (const int*)d_in[4];
  const int*   cl2  = (const int*)d_in[5];
  const float* W01  = (const float*)d_in[9];
  const float* u01  = (const float*)d_in[10];
  const float* c01  = (const float*)d_in[11];
  const float* b01  = (const float*)d_in[12];
  const float* sW01 = (const float*)d_in[13];
  const float* sb01 = (const float*)d_in[14];
  const float* g01  = (const float*)d_in[15];
  const float* be01 = (const float*)d_in[16];
  const float* Ws   = (const float*)d_in[17];
  const float* us   = (const float*)d_in[18];
  const float* cs   = (const float*)d_in[19];
  const float* bs   = (const float*)d_in[20];
  const float* gs   = (const float*)d_in[21];
  const float* bes  = (const float*)d_in[22];
  const float* Wc   = (const float*)d_in[23];
  const float* uc   = (const float*)d_in[24];
  const float* cc   = (const float*)d_in[25];
  const float* bc   = (const float*)d_in[26];
  const float* sWc  = (const float*)d_in[27];
  const float* sbc  = (const float*)d_in[28];
  const float* gc   = (const float*)d_in[29];
  const float* bec  = (const float*)d_in[30];
  const float* Wo   = (const float*)d_in[31];
  const float* uo   = (const float*)d_in[32];
  const float* co   = (const float*)d_in[33];
  const float* bo   = (const float*)d_in[34];
  const float* sWo  = (const float*)d_in[35];
  const float* sbo  = (const float*)d_in[36];

  const int N0 = in_sizes[0] / 4;
  const int nE0 = in_sizes[1] / 2;
  const int nE1 = in_sizes[2] / 2;
  const int nE2 = in_sizes[3] / 2;
  const int N1 = 5000, N2 = 1250;

  // ---- workspace layout ----
  float* fp = (float*)d_ws;
  auto alloc_f = [&](size_t n) { n = (n + 15) & ~(size_t)15; float* p = fp; fp += n; return p; };
  auto alloc_h = [&](size_t n) { return (u16*)alloc_f((n + 1) / 2); };
  float* G = alloc_f((size_t)N0 * 704);
  u16* a0Ah = alloc_h((size_t)N0 * HALF);
  u16* a0Al = alloc_h((size_t)N0 * HALF);
  u16* a0Bh = alloc_h((size_t)N0 * HALF);
  u16* a0Bl = alloc_h((size_t)N0 * HALF);
  u16* a1Ah = alloc_h((size_t)N1 * HALF);
  u16* a1Al = alloc_h((size_t)N1 * HALF);
  u16* a1Bh = alloc_h((size_t)N1 * HALF);
  u16* a1Bl = alloc_h((size_t)N1 * HALF);
  u16* a2Ah = alloc_h((size_t)N2 * HALF);
  u16* a2Al = alloc_h((size_t)N2 * HALF);
  u16* a2Bh = alloc_h((size_t)N2 * HALF);
  u16* a2Bl = alloc_h((size_t)N2 * HALF);
  u16* xbh  = alloc_h((size_t)N0 * 32);
  u16* xbl  = alloc_h((size_t)N0 * 32);
  u16* Bp01h = alloc_h((size_t)704 * 32);
  u16* Bp01l = alloc_h((size_t)704 * 32);
  u16 *Bpsh[10], *Bpsl[10];
  for (int i = 0; i < 10; ++i) {
    Bpsh[i] = alloc_h((size_t)576 * 160);
    Bpsl[i] = alloc_h((size_t)576 * 160);
  }
  u16* Bpc0h = alloc_h((size_t)704 * 320);
  u16* Bpc0l = alloc_h((size_t)704 * 320);
  u16* Bpc1h = alloc_h((size_t)704 * 320);
  u16* Bpc1l = alloc_h((size_t)704 * 320);
  u16* Bpoh  = alloc_h((size_t)64 * 160);
  u16* Bpol  = alloc_h((size_t)64 * 160);
  int* ipb = (int*)fp;
  auto alloc_i = [&](size_t n) { int* p = ipb; ipb += n; return p; };
  int* rp0  = alloc_i(N0 + 1);
  int* sl0  = alloc_i(nE0);
  int* rp1  = alloc_i(N1 + 1);
  int* sl1  = alloc_i(nE1);
  int* rp2  = alloc_i(N2 + 1);
  int* sl2  = alloc_i(nE2);
  int* rpc1 = alloc_i(N1 + 1);
  int* slc1 = alloc_i(N0);
  int* rpc2 = alloc_i(N2 + 1);
  int* slc2 = alloc_i(N1);
  int* cur  = alloc_i(N0 + 1);
  if ((size_t)((char*)ipb - (char*)d_ws) > ws_size) return;

  auto cdiv = [](int a, int b) { return (a + b - 1) / b; };

  // ---- CSR builds ----
  auto build_edges = [&](const int* ei, int nE, int nN, int* rp, int* sl) {
    k_zero_i32<<<cdiv(nN, 256), 256, 0, stream>>>(cur, nN);
    k_hist<<<cdiv(nE, 256), 256, 0, stream>>>(ei + nE, nE, cur);
    k_exscan<<<1, 1024, 0, stream>>>(cur, nN, rp);
    k_copy_i32<<<cdiv(nN, 256), 256, 0, stream>>>(rp, cur, nN);
    k_scatter_edges<<<cdiv(nE, 256), 256, 0, stream>>>(ei, ei + nE, nE, cur, sl);
  };
  auto build_cl = [&](const int* cl, int nSrc, int nN, int* rp, int* sl) {
    k_zero_i32<<<cdiv(nN, 256), 256, 0, stream>>>(cur, nN);
    k_hist<<<cdiv(nSrc, 256), 256, 0, stream>>>(cl, nSrc, cur);
    k_exscan<<<1, 1024, 0, stream>>>(cur, nN, rp);
    k_copy_i32<<<cdiv(nN, 256), 256, 0, stream>>>(rp, cur, nN);
    k_scatter_nodes<<<cdiv(nSrc, 256), 256, 0, stream>>>(cl, nSrc, cur, sl);
  };
  build_edges(e0, nE0, N0, rp0, sl0);
  build_edges(e1, nE1, N1, rp1, sl1);
  build_edges(e2, nE2, N2, rp2, sl2);
  build_cl(cl1, N0, N1, rpc1, slc1);
  build_cl(cl2, N1, N2, rpc2, slc2);

  // ---- weight packing ----
  auto pack = [&](const float* W, const float* u, const float* sW, u16* Bh, u16* Bl,
                  int C, int K1, int K2, int Kpad, int Mld) {
    int tot = Mld * Kpad;
    k_pack<<<cdiv(tot, 256), 256, 0, stream>>>(W, u, sW, Bh, Bl, C, K1, K2, Kpad, Mld);
  };
  pack(W01, u01, sW01, Bp01h, Bp01l, CC, 4, 0, 32, 704);
  for (int i = 0; i < 10; ++i)
    pack(Ws + (size_t)i * CC * HH * CC, us + (size_t)i * CC * HH, nullptr,
         Bpsh[i], Bpsl[i], CC, CC, 0, 160, 576);
  pack(Wc, uc, sWc, Bpc0h, Bpc0l, CC, CC, CC, 320, 704);
  pack(Wc + (size_t)2 * CC * HH * CC, uc + (size_t)2 * CC * HH, sWc + (size_t)2 * CC * CC,
       Bpc1h, Bpc1l, CC, CC, CC, 320, 704);
  pack(Wo, uo, sWo, Bpoh, Bpol, 1, CC, 0, 160, 64);
  k_pack_x<<<cdiv(N0 * 32, 256), 256, 0, stream>>>(x, xbh, xbl, N0);

  // conv driver
  auto do_conv = [&](const u16* A1h, const u16* A1l, const u16* A2h, const u16* A2l,
                     const int* amap, int Kpad, int lda1, const u16* Bh, const u16* Bl,
                     int Mld, int n, const int* rp, const int* sl,
                     const float* cp, const float* bp, const float* gp, const float* bep,
                     const u16* skipH, const u16* skipL, const float* sbp,
                     u16* outH, u16* outL) {
    dim3 grid(Mld / 64, cdiv(n, 128));
    k_gemm_mfma<<<grid, 256, 0, stream>>>(A1h, A1l, A2h, A2l, amap, Bh, Bl, G, n, Kpad, lda1, 704);
    k_agg<<<cdiv(n, 4), 256, 0, stream>>>(G, 704, cp, bp, gp, bep, skipH, skipL, sbp,
                                          rp, sl, outH, outL, n, 1);
  };

  auto ci  = [&](int i) { return cs + (size_t)i * HH; };
  auto bi  = [&](int i) { return bs + (size_t)i * CC; };
  auto gi  = [&](int i) { return gs + (size_t)i * CC; };
  auto bei = [&](int i) { return bes + (size_t)i * CC; };

  // conv01: K=4 (padded 32), GEMM skip
  do_conv(xbh, xbl, nullptr, nullptr, nullptr, 32, 32, Bp01h, Bp01l, 704, N0, rp0, sl0,
          c01, b01, g01, be01, nullptr, nullptr, sb01, a0Ah, a0Al);
  // conv02 (identity skip) -> copy0 = a0B
  do_conv(a0Ah, a0Al, nullptr, nullptr, nullptr, 160, HALF, Bpsh[0], Bpsl[0], 576, N0, rp0, sl0,
          ci(0), bi(0), gi(0), bei(0), a0Ah, a0Al, nullptr, a0Bh, a0Bl);
  // pool1
  k_pool<<<cdiv(N1, 4), 256, 0, stream>>>(a0Bh, a0Bl, rpc1, slc1, a1Ah, a1Al, N1);
  // conv11, conv12 (copy1 = a1A after conv12)
  do_conv(a1Ah, a1Al, nullptr, nullptr, nullptr, 160, HALF, Bpsh[1], Bpsl[1], 576, N1, rp1, sl1,
          ci(1), bi(1), gi(1), bei(1), a1Ah, a1Al, nullptr, a1Bh, a1Bl);
  do_conv(a1Bh, a1Bl, nullptr, nullptr, nullptr, 160, HALF, Bpsh[2], Bpsl[2], 576, N1, rp1, sl1,
          ci(2), bi(2), gi(2), bei(2), a1Bh, a1Bl, nullptr, a1Ah, a1Al);
  // pool2
  k_pool<<<cdiv(N2, 4), 256, 0, stream>>>(a1Ah, a1Al, rpc2, slc2, a2Ah, a2Al, N2);
  // conv21, conv22
  do_conv(a2Ah, a2Al, nullptr, nullptr, nullptr, 160, HALF, Bpsh[3], Bpsl[3], 576, N2, rp2, sl2,
          ci(3), bi(3), gi(3), bei(3), a2Ah, a2Al, nullptr, a2Bh, a2Bl);
  do_conv(a2Bh, a2Bl, nullptr, nullptr, nullptr, 160, HALF, Bpsh[4], Bpsl[4], 576, N2, rp2, sl2,
          ci(4), bi(4), gi(4), bei(4), a2Bh, a2Bl, nullptr, a2Ah, a2Al);
  // conv13 on [unpool2(a2A) | a1A], GEMM skip
  do_conv(a2Ah, a2Al, a1Ah, a1Al, cl2, 320, HALF, Bpc0h, Bpc0l, 704, N1, rp1, sl1,
          cc, bc, gc, bec, nullptr, nullptr, sbc, a1Bh, a1Bl);
  // conv14, conv15, conv16
  do_conv(a1Bh, a1Bl, nullptr, nullptr, nullptr, 160, HALF, Bpsh[5], Bpsl[5], 576, N1, rp1, sl1,
          ci(5), bi(5), gi(5), bei(5), a1Bh, a1Bl, nullptr, a1Ah, a1Al);
  do_conv(a1Ah, a1Al, nullptr, nullptr, nullptr, 160, HALF, Bpsh[6], Bpsl[6], 576, N1, rp1, sl1,
          ci(6), bi(6), gi(6), bei(6), a1Ah, a1Al, nullptr, a1Bh, a1Bl);
  do_conv(a1Bh, a1Bl, nullptr, nullptr, nullptr, 160, HALF, Bpsh[7], Bpsl[7], 576, N1, rp1, sl1,
          ci(7), bi(7), gi(7), bei(7), a1Bh, a1Bl, nullptr, a1Ah, a1Al);
  // conv03 on [unpool1(a1A) | a0B], GEMM skip
  do_conv(a1Ah, a1Al, a0Bh, a0Bl, cl1, 320, HALF, Bpc1h, Bpc1l, 704, N0, rp0, sl0,
          cc + HH, bc + CC, gc + CC, bec + CC, nullptr, nullptr, sbc + CC, a0Ah, a0Al);
  // conv04, conv05
  do_conv(a0Ah, a0Al, nullptr, nullptr, nullptr, 160, HALF, Bpsh[8], Bpsl[8], 576, N0, rp0, sl0,
          ci(8), bi(8), gi(8), bei(8), a0Ah, a0Al, nullptr, a0Bh, a0Bl);
  do_conv(a0Bh, a0Bl, nullptr, nullptr, nullptr, 160, HALF, Bpsh[9], Bpsl[9], 576, N0, rp0, sl0,
          ci(9), bi(9), gi(9), bei(9), a0Bh, a0Bl, nullptr, a0Ah, a0Al);
  // conv06: 140 -> 1
  {
    dim3 grid(1, cdiv(N0, 128));
    k_gemm_mfma<<<grid, 256, 0, stream>>>(a0Ah, a0Al, nullptr, nullptr, nullptr,
                                          Bpoh, Bpol, G, N0, 160, HALF, 704);
    k_out<<<cdiv(N0, 4), 256, 0, stream>>>(G, 704, co, bo, sbo, rp0, sl0, (float*)d_out, N0);
  }
}

// Round 4
// 1092.413 us; speedup vs baseline: 2.0564x; 1.1833x over previous
//
#include <hip/hip_runtime.h>
#include <math.h>

#define HH 4
#define CC 140
#define HALF 160   // padded K of one concat half / one plain input

typedef __attribute__((ext_vector_type(8))) short short8;
typedef __attribute__((ext_vector_type(4))) float f32x4;
typedef unsigned short u16;

__device__ inline float b2f(u16 u) {
  union { float f; unsigned u; } v; v.u = ((unsigned)u) << 16; return v.f;
}
__device__ inline u16 f2b(float x) {
  union { float f; unsigned u; } v; v.f = x;
  unsigned r = v.u + 0x7FFFu + ((v.u >> 16) & 1u);
  return (u16)(r >> 16);
}

// ============================ CSR build ============================
__global__ __launch_bounds__(256) void k_zero_i32(int* __restrict__ p, int n) {
  int i = blockIdx.x * 256 + threadIdx.x;
  if (i < n) p[i] = 0;
}
__global__ __launch_bounds__(256) void k_hist(const int* __restrict__ idx, int n,
                                              int* __restrict__ cnt) {
  int i = blockIdx.x * 256 + threadIdx.x;
  if (i < n) atomicAdd(&cnt[idx[i]], 1);
}
__global__ __launch_bounds__(1024) void k_exscan(const int* __restrict__ in, int n,
                                                 int* __restrict__ out) {
  __shared__ int buf[1024];
  __shared__ int carry_s;
  if (threadIdx.x == 0) carry_s = 0;
  __syncthreads();
  for (int base = 0; base < n; base += 1024) {
    int i = base + (int)threadIdx.x;
    int v = (i < n) ? in[i] : 0;
    buf[threadIdx.x] = v;
    __syncthreads();
    int x = v;
    for (int off = 1; off < 1024; off <<= 1) {
      int t = (threadIdx.x >= (unsigned)off) ? buf[threadIdx.x - off] : 0;
      __syncthreads();
      x += t;
      buf[threadIdx.x] = x;
      __syncthreads();
    }
    int carry = carry_s;
    if (i < n) out[i] = carry + x - v;
    __syncthreads();
    if (threadIdx.x == 1023) carry_s = carry + buf[1023];
    __syncthreads();
  }
  if (threadIdx.x == 0) out[n] = carry_s;
}
__global__ __launch_bounds__(256) void k_copy_i32(const int* __restrict__ a,
                                                  int* __restrict__ b, int n) {
  int i = blockIdx.x * 256 + threadIdx.x;
  if (i < n) b[i] = a[i];
}
__global__ __launch_bounds__(256) void k_scatter_edges(const int* __restrict__ src,
                                                       const int* __restrict__ dst, int nE,
                                                       int* __restrict__ cur,
                                                       int* __restrict__ slots) {
  int e = blockIdx.x * 256 + threadIdx.x;
  if (e < nE) {
    int p = atomicAdd(&cur[dst[e]], 1);
    slots[p] = src[e];
  }
}
__global__ __launch_bounds__(256) void k_scatter_nodes(const int* __restrict__ cl, int n,
                                                       int* __restrict__ cur,
                                                       int* __restrict__ slots) {
  int i = blockIdx.x * 256 + threadIdx.x;
  if (i < n) {
    int p = atomicAdd(&cur[cl[i]], 1);
    slots[p] = i;
  }
}

// ============================ weight pack (hi+lo planes) ============================
__global__ __launch_bounds__(256) void k_pack(const float* __restrict__ W,
                                              const float* __restrict__ u,
                                              const float* __restrict__ sW,
                                              u16* __restrict__ Bph, u16* __restrict__ Bpl,
                                              int C, int K1, int K2, int Kpad, int Mld) {
  int idx = blockIdx.x * 256 + threadIdx.x;
  if (idx >= Mld * Kpad) return;
  int col = idx / Kpad, kp = idx - col * Kpad;
  int ksrc = -1;
  if (kp < K1) ksrc = kp;
  else if (kp >= HALF && kp - HALF < K2) ksrc = K1 + (kp - HALF);
  float v = 0.f;
  if (ksrc >= 0) {
    if (col < 4 * C) {
      int c = col >> 2, h = col & 3;
      v = W[(size_t)ksrc * 4 * C + h * C + c];
    } else if (col < 4 * C + 4) {
      v = u[(size_t)ksrc * 4 + (col - 4 * C)];
    } else if (sW && col < 5 * C + 4) {
      v = sW[(size_t)ksrc * C + (col - 4 * C - 4)];
    }
  }
  u16 hi = f2b(v);
  Bph[idx] = hi;
  Bpl[idx] = f2b(v - b2f(hi));
}

__global__ __launch_bounds__(256) void k_pack_x(const float* __restrict__ x,
                                                u16* __restrict__ xh, u16* __restrict__ xl,
                                                int n) {
  int idx = blockIdx.x * 256 + threadIdx.x;
  if (idx >= n * 32) return;
  int i = idx >> 5, c = idx & 31;
  float v = (c < 4) ? x[(size_t)i * 4 + c] : 0.f;
  u16 hi = f2b(v);
  xh[idx] = hi;
  xl[idx] = f2b(v - b2f(hi));
}

// ============================ split-bf16 MFMA GEMM, split output ============================
// (Ah+Al)[N][K] @ (Bh+Bl)^T (AlBl dropped). Output by column:
//   gc < yEnd            -> Gy bf16, row-stride yEnd
//   yEnd <= gc < yEnd+4  -> Gl f32, row-stride 4   (attention logits)
//   yEnd+4 <= gc < +Cs   -> Gs f32, row-stride Cs  (GEMM skip)
__global__ __launch_bounds__(256) void k_gemm_mfma(
    const u16* __restrict__ A1h, const u16* __restrict__ A1l,
    const u16* __restrict__ A2h, const u16* __restrict__ A2l,
    const int* __restrict__ amap,
    const u16* __restrict__ Bph, const u16* __restrict__ Bpl,
    u16* __restrict__ Gy, float* __restrict__ Gl, float* __restrict__ Gs,
    int yEnd, int Cs, int N, int Kpad, int lda1) {
  __shared__ __align__(16) u16 Ash[128 * 32];
  __shared__ __align__(16) u16 Asl[128 * 32];
  __shared__ __align__(16) u16 Bsh[64 * 32];
  __shared__ __align__(16) u16 Bsl[64 * 32];
  const int tid = threadIdx.x;
  const int row0 = blockIdx.y * 128, col0 = blockIdx.x * 64;
  const int w = tid >> 6, lane = tid & 63;
  const int wm = w >> 1, wn = w & 1;
  const int arow = lane & 15, chunk = lane >> 4;
  const int swz = chunk ^ (arow & 3);
  f32x4 acc[4][2];
#pragma unroll
  for (int i = 0; i < 4; ++i)
#pragma unroll
    for (int j = 0; j < 2; ++j) acc[i][j] = (f32x4){0.f, 0.f, 0.f, 0.f};
  const int sar = tid >> 1;
  const int sak = (tid & 1) * 16;
  const int sbc = tid >> 2;
  const int sbk = (tid & 3) * 8;
  for (int k0 = 0; k0 < Kpad; k0 += 32) {
    {
      int gr = row0 + sar;
      short8 v0h = {0,0,0,0,0,0,0,0}, v1h = v0h, v0l = v0h, v1l = v0h;
      if (gr < N) {
        int kp0 = k0 + sak;
        const u16 *bh_, *bl_;
        int rr, kk, ld;
        if (A2h && kp0 >= HALF) {
          bh_ = A2h; bl_ = A2l; rr = gr; kk = kp0 - HALF; ld = HALF;
        } else {
          bh_ = A1h; bl_ = A1l; rr = amap ? amap[gr] : gr; kk = kp0; ld = lda1;
        }
        const u16* ph = bh_ + (size_t)rr * ld + kk;
        const u16* pl = bl_ + (size_t)rr * ld + kk;
        v0h = *(const short8*)(ph);
        v1h = *(const short8*)(ph + 8);
        v0l = *(const short8*)(pl);
        v1l = *(const short8*)(pl + 8);
      }
      int c0 = sak >> 3, sw = sar & 3;
      *(short8*)(Ash + sar * 32 + ((c0 ^ sw) << 3)) = v0h;
      *(short8*)(Ash + sar * 32 + (((c0 + 1) ^ sw) << 3)) = v1h;
      *(short8*)(Asl + sar * 32 + ((c0 ^ sw) << 3)) = v0l;
      *(short8*)(Asl + sar * 32 + (((c0 + 1) ^ sw) << 3)) = v1l;
    }
    {
      int gc = col0 + sbc;
      short8 vh = *(const short8*)(Bph + (size_t)gc * Kpad + k0 + sbk);
      short8 vl = *(const short8*)(Bpl + (size_t)gc * Kpad + k0 + sbk);
      int c = sbk >> 3, sw = sbc & 3;
      *(short8*)(Bsh + sbc * 32 + ((c ^ sw) << 3)) = vh;
      *(short8*)(Bsl + sbc * 32 + ((c ^ sw) << 3)) = vl;
    }
    __syncthreads();
    short8 bh[2], bl[2], ah[4], al[4];
#pragma unroll
    for (int ni = 0; ni < 2; ++ni) {
      int col = wn * 32 + ni * 16 + arow;
      bh[ni] = *(const short8*)(Bsh + col * 32 + (swz << 3));
      bl[ni] = *(const short8*)(Bsl + col * 32 + (swz << 3));
    }
#pragma unroll
    for (int mi = 0; mi < 4; ++mi) {
      int r = wm * 64 + mi * 16 + arow;
      ah[mi] = *(const short8*)(Ash + r * 32 + (swz << 3));
      al[mi] = *(const short8*)(Asl + r * 32 + (swz << 3));
    }
#pragma unroll
    for (int mi = 0; mi < 4; ++mi)
#pragma unroll
      for (int ni = 0; ni < 2; ++ni)
        acc[mi][ni] = __builtin_amdgcn_mfma_f32_16x16x32_bf16(ah[mi], bh[ni], acc[mi][ni], 0, 0, 0);
#pragma unroll
    for (int mi = 0; mi < 4; ++mi)
#pragma unroll
      for (int ni = 0; ni < 2; ++ni)
        acc[mi][ni] = __builtin_amdgcn_mfma_f32_16x16x32_bf16(ah[mi], bl[ni], acc[mi][ni], 0, 0, 0);
#pragma unroll
    for (int mi = 0; mi < 4; ++mi)
#pragma unroll
      for (int ni = 0; ni < 2; ++ni)
        acc[mi][ni] = __builtin_amdgcn_mfma_f32_16x16x32_bf16(al[mi], bh[ni], acc[mi][ni], 0, 0, 0);
    __syncthreads();
  }
  const int crow = (lane >> 4) * 4, ccol = lane & 15;
#pragma unroll
  for (int mi = 0; mi < 4; ++mi) {
    int gr0 = row0 + wm * 64 + mi * 16 + crow;
#pragma unroll
    for (int ni = 0; ni < 2; ++ni) {
      int gc = col0 + wn * 32 + ni * 16 + ccol;
#pragma unroll
      for (int j = 0; j < 4; ++j) {
        int gr = gr0 + j;
        if (gr >= N) continue;
        float v = acc[mi][ni][j];
        if (gc < yEnd) Gy[(size_t)gr * yEnd + gc] = f2b(v);
        else if (gc < yEnd + 4) Gl[(size_t)gr * 4 + (gc - yEnd)] = v;
        else if (gc < yEnd + 4 + Cs) Gs[(size_t)gr * Cs + (gc - yEnd - 4)] = v;
      }
    }
  }
}

// ============================ fused FeaSt agg + LN + skip + relu ============================
// Gy bf16 (n,560) head-minor; Gl f32 (n,4) logits; Gs f32 (n,CC) GEMM skip (or null)
__global__ __launch_bounds__(256) void k_agg(
    const u16* __restrict__ Gy, const float* __restrict__ Gl,
    const float* __restrict__ cv, const float* __restrict__ bias,
    const float* __restrict__ g, const float* __restrict__ be,
    const u16* __restrict__ inH, const u16* __restrict__ inL,  // identity skip (or null)
    const float* __restrict__ Gs, const float* __restrict__ sb, // GEMM skip
    const int* __restrict__ rp, const int* __restrict__ sl,
    u16* __restrict__ outH, u16* __restrict__ outL, int n, int relu) {
  int wid = blockIdx.x * 4 + ((int)threadIdx.x >> 6);
  int lane = threadIdx.x & 63;
  if (wid >= n) return;
  float4 la = *(const float4*)(Gl + (size_t)wid * 4);
  float d0 = cv[0] - la.x, d1 = cv[1] - la.y;
  float d2 = cv[2] - la.z, d3 = cv[3] - la.w;
  int eb = rp[wid], ee = rp[wid + 1];
  const int c0 = lane, c1 = lane + 64, c2 = lane + 128;
  const bool h2v = c2 < CC;
  float acc0 = 0.f, acc1 = 0.f, acc2 = 0.f;
#pragma unroll 2
  for (int e = eb; e < ee; ++e) {
    int s = sl[e];
    float4 lg = *(const float4*)(Gl + (size_t)s * 4);
    float t0 = lg.x + d0, t1 = lg.y + d1, t2 = lg.z + d2, t3 = lg.w + d3;
    float m = fmaxf(fmaxf(t0, t1), fmaxf(t2, t3));
    float q0 = __expf(t0 - m), q1 = __expf(t1 - m), q2 = __expf(t2 - m), q3 = __expf(t3 - m);
    float qi = 1.f / (q0 + q1 + q2 + q3);
    q0 *= qi; q1 *= qi; q2 *= qi; q3 *= qi;
    const u16* gy = Gy + (size_t)s * 560;
    ushort4 y0 = *(const ushort4*)(gy + (c0 << 2));
    acc0 += q0 * b2f(y0.x) + q1 * b2f(y0.y) + q2 * b2f(y0.z) + q3 * b2f(y0.w);
    ushort4 y1 = *(const ushort4*)(gy + (c1 << 2));
    acc1 += q0 * b2f(y1.x) + q1 * b2f(y1.y) + q2 * b2f(y1.z) + q3 * b2f(y1.w);
    if (h2v) {
      ushort4 y2 = *(const ushort4*)(gy + (c2 << 2));
      acc2 += q0 * b2f(y2.x) + q1 * b2f(y2.y) + q2 * b2f(y2.z) + q3 * b2f(y2.w);
    }
  }
  int cnt = ee - eb;
  float inv = 1.f / (float)(cnt > 1 ? cnt : 1);
  float v0 = acc0 * inv + bias[c0];
  float v1 = acc1 * inv + bias[c1];
  float v2 = h2v ? acc2 * inv + bias[c2] : 0.f;
  if (g) {
    float s1 = v0 + v1 + v2;
    float s2 = v0 * v0 + v1 * v1 + v2 * v2;
#pragma unroll
    for (int off = 32; off > 0; off >>= 1) {
      s1 += __shfl_xor(s1, off);
      s2 += __shfl_xor(s2, off);
    }
    float mu = s1 * (1.0f / CC);
    float var = s2 * (1.0f / CC) - mu * mu;
    float r = rsqrtf(var + 1e-5f);
    v0 = (v0 - mu) * r * g[c0] + be[c0];
    v1 = (v1 - mu) * r * g[c1] + be[c1];
    if (h2v) v2 = (v2 - mu) * r * g[c2] + be[c2];
  }
  if (inH) {
    const u16* ih = inH + (size_t)wid * HALF;
    const u16* il = inL + (size_t)wid * HALF;
    v0 += b2f(ih[c0]) + b2f(il[c0]);
    v1 += b2f(ih[c1]) + b2f(il[c1]);
    if (h2v) v2 += b2f(ih[c2]) + b2f(il[c2]);
  } else {
    const float* gsr = Gs + (size_t)wid * CC;
    v0 += gsr[c0] + sb[c0];
    v1 += gsr[c1] + sb[c1];
    if (h2v) v2 += gsr[c2] + sb[c2];
  }
  if (relu) {
    v0 = fmaxf(v0, 0.f); v1 = fmaxf(v1, 0.f); v2 = fmaxf(v2, 0.f);
  }
  u16* oh = outH + (size_t)wid * HALF;
  u16* ol = outL + (size_t)wid * HALF;
  u16 h0 = f2b(v0); oh[c0] = h0; ol[c0] = f2b(v0 - b2f(h0));
  u16 h1 = f2b(v1); oh[c1] = h1; ol[c1] = f2b(v1 - b2f(h1));
  if (h2v) {
    u16 h2 = f2b(v2); oh[c2] = h2; ol[c2] = f2b(v2 - b2f(h2));
  } else if (c2 < HALF) {
    oh[c2] = 0; ol[c2] = 0;
  }
}

// conv06: Gy bf16 (n,4) = Y heads; Gl f32 logits; Gs f32 (n,1) skip
__global__ __launch_bounds__(256) void k_out(
    const u16* __restrict__ Gy, const float* __restrict__ Gl,
    const float* __restrict__ cv, const float* __restrict__ bo,
    const float* __restrict__ Gs, const float* __restrict__ sbo,
    const int* __restrict__ rp, const int* __restrict__ sl,
    float* __restrict__ out, int n) {
  int wid = blockIdx.x * 4 + ((int)threadIdx.x >> 6);
  int lane = threadIdx.x & 63;
  if (wid >= n) return;
  float4 la = *(const float4*)(Gl + (size_t)wid * 4);
  float d0 = cv[0] - la.x, d1 = cv[1] - la.y;
  float d2 = cv[2] - la.z, d3 = cv[3] - la.w;
  int eb = rp[wid], ee = rp[wid + 1];
  float part = 0.f;
  for (int e = eb + lane; e < ee; e += 64) {
    int s = sl[e];
    float4 lg = *(const float4*)(Gl + (size_t)s * 4);
    float t0 = lg.x + d0, t1 = lg.y + d1, t2 = lg.z + d2, t3 = lg.w + d3;
    float m = fmaxf(fmaxf(t0, t1), fmaxf(t2, t3));
    float q0 = __expf(t0 - m), q1 = __expf(t1 - m), q2 = __expf(t2 - m), q3 = __expf(t3 - m);
    float qi = 1.f / (q0 + q1 + q2 + q3);
    ushort4 y = *(const ushort4*)(Gy + (size_t)s * 4);
    part += (q0 * b2f(y.x) + q1 * b2f(y.y) + q2 * b2f(y.z) + q3 * b2f(y.w)) * qi;
  }
#pragma unroll
  for (int off = 32; off > 0; off >>= 1) part += __shfl_xor(part, off);
  if (lane == 0) {
    int cnt = ee - eb;
    out[wid] = part / (float)(cnt > 1 ? cnt : 1) + bo[0] + Gs[wid] + sbo[0];
  }
}

// ============================ pool (split planes in/out) ============================
__global__ __launch_bounds__(256) void k_pool(const u16* __restrict__ inH,
                                              const u16* __restrict__ inL,
                                              const int* __restrict__ rp,
                                              const int* __restrict__ sl,
                                              u16* __restrict__ outH,
                                              u16* __restrict__ outL, int nseg) {
  int wid = blockIdx.x * 4 + ((int)threadIdx.x >> 6);
  int lane = threadIdx.x & 63;
  if (wid >= nseg) return;
  int a = rp[wid], b = rp[wid + 1];
  const int c0 = lane, c1 = lane + 64, c2 = lane + 128;
  const bool h2v = c2 < CC;
  float acc0 = 0.f, acc1 = 0.f, acc2 = 0.f;
  for (int s = a; s < b; ++s) {
    size_t off = (size_t)sl[s] * HALF;
    acc0 += b2f(inH[off + c0]) + b2f(inL[off + c0]);
    acc1 += b2f(inH[off + c1]) + b2f(inL[off + c1]);
    if (h2v) acc2 += b2f(inH[off + c2]) + b2f(inL[off + c2]);
  }
  int cnt = b - a;
  float inv = 1.f / (float)(cnt > 1 ? cnt : 1);
  float v0 = acc0 * inv, v1 = acc1 * inv, v2 = acc2 * inv;
  u16* oh = outH + (size_t)wid * HALF;
  u16* ol = outL + (size_t)wid * HALF;
  u16 h0 = f2b(v0); oh[c0] = h0; ol[c0] = f2b(v0 - b2f(h0));
  u16 h1 = f2b(v1); oh[c1] = h1; ol[c1] = f2b(v1 - b2f(h1));
  if (h2v) {
    u16 h2 = f2b(v2); oh[c2] = h2; ol[c2] = f2b(v2 - b2f(h2));
  } else if (c2 < HALF) {
    oh[c2] = 0; ol[c2] = 0;
  }
}

// ============================ host ============================
extern "C" void kernel_launch(void* const* d_in, const int* in_sizes, int n_in,
                              void* d_out, int out_size, void* d_ws, size_t ws_size,
                              hipStream_t stream) {
  (void)n_in; (void)out_size;
  const float* x    = (const float*)d_in[0];
  const int*   e0   = (const int*)d_in[1];
  const int*   e1   = (const int*)d_in[2];
  const int*   e2   = (const int*)d_in[3];
  const int*   cl1  = (const int*)d_in[4];
  const int*   cl2  = (const int*)d_in[5];
  const float* W01  = (const float*)d_in[9];
  const float* u01  = (const float*)d_in[10];
  const float* c01  = (const float*)d_in[11];
  const float* b01  = (const float*)d_in[12];
  const float* sW01 = (const float*)d_in[13];
  const float* sb01 = (const float*)d_in[14];
  const float* g01  = (const float*)d_in[15];
  const float* be01 = (const float*)d_in[16];
  const float* Ws   = (const float*)d_in[17];
  const float* us   = (const float*)d_in[18];
  const float* cs   = (const float*)d_in[19];
  const float* bs   = (const float*)d_in[20];
  const float* gs   = (const float*)d_in[21];
  const float* bes  = (const float*)d_in[22];
  const float* Wc   = (const float*)d_in[23];
  const float* uc   = (const float*)d_in[24];
  const float* cc   = (const float*)d_in[25];
  const float* bc   = (const float*)d_in[26];
  const float* sWc  = (const float*)d_in[27];
  const float* sbc  = (const float*)d_in[28];
  const float* gc   = (const float*)d_in[29];
  const float* bec  = (const float*)d_in[30];
  const float* Wo   = (const float*)d_in[31];
  const float* uo   = (const float*)d_in[32];
  const float* co   = (const float*)d_in[33];
  const float* bo   = (const float*)d_in[34];
  const float* sWo  = (const float*)d_in[35];
  const float* sbo  = (const float*)d_in[36];

  const int N0 = in_sizes[0] / 4;
  const int nE0 = in_sizes[1] / 2;
  const int nE1 = in_sizes[2] / 2;
  const int nE2 = in_sizes[3] / 2;
  const int N1 = 5000, N2 = 1250;

  // ---- workspace layout ----
  float* fp = (float*)d_ws;
  auto alloc_f = [&](size_t n) { n = (n + 15) & ~(size_t)15; float* p = fp; fp += n; return p; };
  auto alloc_h = [&](size_t n) { return (u16*)alloc_f((n + 1) / 2); };
  u16*   Gy = alloc_h((size_t)N0 * 560);
  float* Gl = alloc_f((size_t)N0 * 4);
  float* Gs = alloc_f((size_t)N0 * CC);
  u16* a0Ah = alloc_h((size_t)N0 * HALF);
  u16* a0Al = alloc_h((size_t)N0 * HALF);
  u16* a0Bh = alloc_h((size_t)N0 * HALF);
  u16* a0Bl = alloc_h((size_t)N0 * HALF);
  u16* a1Ah = alloc_h((size_t)N1 * HALF);
  u16* a1Al = alloc_h((size_t)N1 * HALF);
  u16* a1Bh = alloc_h((size_t)N1 * HALF);
  u16* a1Bl = alloc_h((size_t)N1 * HALF);
  u16* a2Ah = alloc_h((size_t)N2 * HALF);
  u16* a2Al = alloc_h((size_t)N2 * HALF);
  u16* a2Bh = alloc_h((size_t)N2 * HALF);
  u16* a2Bl = alloc_h((size_t)N2 * HALF);
  u16* xbh  = alloc_h((size_t)N0 * 32);
  u16* xbl  = alloc_h((size_t)N0 * 32);
  u16* Bp01h = alloc_h((size_t)704 * 32);
  u16* Bp01l = alloc_h((size_t)704 * 32);
  u16 *Bpsh[10], *Bpsl[10];
  for (int i = 0; i < 10; ++i) {
    Bpsh[i] = alloc_h((size_t)576 * 160);
    Bpsl[i] = alloc_h((size_t)576 * 160);
  }
  u16* Bpc0h = alloc_h((size_t)704 * 320);
  u16* Bpc0l = alloc_h((size_t)704 * 320);
  u16* Bpc1h = alloc_h((size_t)704 * 320);
  u16* Bpc1l = alloc_h((size_t)704 * 320);
  u16* Bpoh  = alloc_h((size_t)64 * 160);
  u16* Bpol  = alloc_h((size_t)64 * 160);
  int* ipb = (int*)fp;
  auto alloc_i = [&](size_t n) { int* p = ipb; ipb += n; return p; };
  int* rp0  = alloc_i(N0 + 1);
  int* sl0  = alloc_i(nE0);
  int* rp1  = alloc_i(N1 + 1);
  int* sl1  = alloc_i(nE1);
  int* rp2  = alloc_i(N2 + 1);
  int* sl2  = alloc_i(nE2);
  int* rpc1 = alloc_i(N1 + 1);
  int* slc1 = alloc_i(N0);
  int* rpc2 = alloc_i(N2 + 1);
  int* slc2 = alloc_i(N1);
  int* cur  = alloc_i(N0 + 1);
  if ((size_t)((char*)ipb - (char*)d_ws) > ws_size) return;

  auto cdiv = [](int a, int b) { return (a + b - 1) / b; };

  // ---- CSR builds ----
  auto build_edges = [&](const int* ei, int nE, int nN, int* rp, int* sl) {
    k_zero_i32<<<cdiv(nN, 256), 256, 0, stream>>>(cur, nN);
    k_hist<<<cdiv(nE, 256), 256, 0, stream>>>(ei + nE, nE, cur);
    k_exscan<<<1, 1024, 0, stream>>>(cur, nN, rp);
    k_copy_i32<<<cdiv(nN, 256), 256, 0, stream>>>(rp, cur, nN);
    k_scatter_edges<<<cdiv(nE, 256), 256, 0, stream>>>(ei, ei + nE, nE, cur, sl);
  };
  auto build_cl = [&](const int* cl, int nSrc, int nN, int* rp, int* sl) {
    k_zero_i32<<<cdiv(nN, 256), 256, 0, stream>>>(cur, nN);
    k_hist<<<cdiv(nSrc, 256), 256, 0, stream>>>(cl, nSrc, cur);
    k_exscan<<<1, 1024, 0, stream>>>(cur, nN, rp);
    k_copy_i32<<<cdiv(nN, 256), 256, 0, stream>>>(rp, cur, nN);
    k_scatter_nodes<<<cdiv(nSrc, 256), 256, 0, stream>>>(cl, nSrc, cur, sl);
  };
  build_edges(e0, nE0, N0, rp0, sl0);
  build_edges(e1, nE1, N1, rp1, sl1);
  build_edges(e2, nE2, N2, rp2, sl2);
  build_cl(cl1, N0, N1, rpc1, slc1);
  build_cl(cl2, N1, N2, rpc2, slc2);

  // ---- weight packing ----
  auto pack = [&](const float* W, const float* u, const float* sW, u16* Bh, u16* Bl,
                  int C, int K1, int K2, int Kpad, int Mld) {
    int tot = Mld * Kpad;
    k_pack<<<cdiv(tot, 256), 256, 0, stream>>>(W, u, sW, Bh, Bl, C, K1, K2, Kpad, Mld);
  };
  pack(W01, u01, sW01, Bp01h, Bp01l, CC, 4, 0, 32, 704);
  for (int i = 0; i < 10; ++i)
    pack(Ws + (size_t)i * CC * HH * CC, us + (size_t)i * CC * HH, nullptr,
         Bpsh[i], Bpsl[i], CC, CC, 0, 160, 576);
  pack(Wc, uc, sWc, Bpc0h, Bpc0l, CC, CC, CC, 320, 704);
  pack(Wc + (size_t)2 * CC * HH * CC, uc + (size_t)2 * CC * HH, sWc + (size_t)2 * CC * CC,
       Bpc1h, Bpc1l, CC, CC, CC, 320, 704);
  pack(Wo, uo, sWo, Bpoh, Bpol, 1, CC, 0, 160, 64);
  k_pack_x<<<cdiv(N0 * 32, 256), 256, 0, stream>>>(x, xbh, xbl, N0);

  // conv driver
  auto do_conv = [&](const u16* A1h, const u16* A1l, const u16* A2h, const u16* A2l,
                     const int* amap, int Kpad, int lda1, const u16* Bh, const u16* Bl,
                     int Mld, bool hasSkip, int n, const int* rp, const int* sl,
                     const float* cp, const float* bp, const float* gp, const float* bep,
                     const u16* skipH, const u16* skipL, const float* sbp,
                     u16* outH, u16* outL) {
    dim3 grid(Mld / 64, cdiv(n, 128));
    k_gemm_mfma<<<grid, 256, 0, stream>>>(A1h, A1l, A2h, A2l, amap, Bh, Bl,
                                          Gy, Gl, Gs, 560, hasSkip ? CC : 0, n, Kpad, lda1);
    k_agg<<<cdiv(n, 4), 256, 0, stream>>>(Gy, Gl, cp, bp, gp, bep, skipH, skipL, Gs, sbp,
                                          rp, sl, outH, outL, n, 1);
  };

  auto ci  = [&](int i) { return cs + (size_t)i * HH; };
  auto bi  = [&](int i) { return bs + (size_t)i * CC; };
  auto gi  = [&](int i) { return gs + (size_t)i * CC; };
  auto bei = [&](int i) { return bes + (size_t)i * CC; };

  // conv01: K=4 (padded 32), GEMM skip
  do_conv(xbh, xbl, nullptr, nullptr, nullptr, 32, 32, Bp01h, Bp01l, 704, true, N0, rp0, sl0,
          c01, b01, g01, be01, nullptr, nullptr, sb01, a0Ah, a0Al);
  // conv02 (identity skip) -> copy0 = a0B
  do_conv(a0Ah, a0Al, nullptr, nullptr, nullptr, 160, HALF, Bpsh[0], Bpsl[0], 576, false,
          N0, rp0, sl0, ci(0), bi(0), gi(0), bei(0), a0Ah, a0Al, nullptr, a0Bh, a0Bl);
  // pool1
  k_pool<<<cdiv(N1, 4), 256, 0, stream>>>(a0Bh, a0Bl, rpc1, slc1, a1Ah, a1Al, N1);
  // conv11, conv12 (copy1 = a1A after conv12)
  do_conv(a1Ah, a1Al, nullptr, nullptr, nullptr, 160, HALF, Bpsh[1], Bpsl[1], 576, false,
          N1, rp1, sl1, ci(1), bi(1), gi(1), bei(1), a1Ah, a1Al, nullptr, a1Bh, a1Bl);
  do_conv(a1Bh, a1Bl, nullptr, nullptr, nullptr, 160, HALF, Bpsh[2], Bpsl[2], 576, false,
          N1, rp1, sl1, ci(2), bi(2), gi(2), bei(2), a1Bh, a1Bl, nullptr, a1Ah, a1Al);
  // pool2
  k_pool<<<cdiv(N2, 4), 256, 0, stream>>>(a1Ah, a1Al, rpc2, slc2, a2Ah, a2Al, N2);
  // conv21, conv22
  do_conv(a2Ah, a2Al, nullptr, nullptr, nullptr, 160, HALF, Bpsh[3], Bpsl[3], 576, false,
          N2, rp2, sl2, ci(3), bi(3), gi(3), bei(3), a2Ah, a2Al, nullptr, a2Bh, a2Bl);
  do_conv(a2Bh, a2Bl, nullptr, nullptr, nullptr, 160, HALF, Bpsh[4], Bpsl[4], 576, false,
          N2, rp2, sl2, ci(4), bi(4), gi(4), bei(4), a2Bh, a2Bl, nullptr, a2Ah, a2Al);
  // conv13 on [unpool2(a2A) | a1A], GEMM skip
  do_conv(a2Ah, a2Al, a1Ah, a1Al, cl2, 320, HALF, Bpc0h, Bpc0l, 704, true, N1, rp1, sl1,
          cc, bc, gc, bec, nullptr, nullptr, sbc, a1Bh, a1Bl);
  // conv14, conv15, conv16
  do_conv(a1Bh, a1Bl, nullptr, nullptr, nullptr, 160, HALF, Bpsh[5], Bpsl[5], 576, false,
          N1, rp1, sl1, ci(5), bi(5), gi(5), bei(5), a1Bh, a1Bl, nullptr, a1Ah, a1Al);
  do_conv(a1Ah, a1Al, nullptr, nullptr, nullptr, 160, HALF, Bpsh[6], Bpsl[6], 576, false,
          N1, rp1, sl1, ci(6), bi(6), gi(6), bei(6), a1Ah, a1Al, nullptr, a1Bh, a1Bl);
  do_conv(a1Bh, a1Bl, nullptr, nullptr, nullptr, 160, HALF, Bpsh[7], Bpsl[7], 576, false,
          N1, rp1, sl1, ci(7), bi(7), gi(7), bei(7), a1Bh, a1Bl, nullptr, a1Ah, a1Al);
  // conv03 on [unpool1(a1A) | a0B], GEMM skip
  do_conv(a1Ah, a1Al, a0Bh, a0Bl, cl1, 320, HALF, Bpc1h, Bpc1l, 704, true, N0, rp0, sl0,
          cc + HH, bc + CC, gc + CC, bec + CC, nullptr, nullptr, sbc + CC, a0Ah, a0Al);
  // conv04, conv05
  do_conv(a0Ah, a0Al, nullptr, nullptr, nullptr, 160, HALF, Bpsh[8], Bpsl[8], 576, false,
          N0, rp0, sl0, ci(8), bi(8), gi(8), bei(8), a0Ah, a0Al, nullptr, a0Bh, a0Bl);
  do_conv(a0Bh, a0Bl, nullptr, nullptr, nullptr, 160, HALF, Bpsh[9], Bpsl[9], 576, false,
          N0, rp0, sl0, ci(9), bi(9), gi(9), bei(9), a0Bh, a0Bl, nullptr, a0Ah, a0Al);
  // conv06: 140 -> 1   (Gy stride 4, logits in Gl, skip in Gs col 0)
  {
    dim3 grid(1, cdiv(N0, 128));
    k_gemm_mfma<<<grid, 256, 0, stream>>>(a0Ah, a0Al, nullptr, nullptr, nullptr,
                                          Bpoh, Bpol, Gy, Gl, Gs, 4, 1, N0, 160, HALF);
    k_out<<<cdiv(N0, 4), 256, 0, stream>>>(Gy, Gl, co, bo, Gs, sbo, rp0, sl0, (float*)d_out, N0);
  }
}

// Round 6
// 877.698 us; speedup vs baseline: 2.5594x; 1.2446x over previous
//
#include <hip/hip_runtime.h>
#include <math.h>

#define HH 4
#define CC 140
#define HALF 160   // padded K of one concat half / one plain input

typedef __attribute__((ext_vector_type(8))) short short8;
typedef __attribute__((ext_vector_type(4))) float f32x4;
typedef __attribute__((ext_vector_type(2))) _Float16 h2;
typedef unsigned short u16;

__device__ inline float b2f(u16 u) {
  union { float f; unsigned u; } v; v.u = ((unsigned)u) << 16; return v.f;
}
__device__ inline u16 f2b(float x) {
  union { float f; unsigned u; } v; v.f = x;
  unsigned r = v.u + 0x7FFFu + ((v.u >> 16) & 1u);
  return (u16)(r >> 16);
}
__device__ inline u16 f2h(float x) {
  union { _Float16 h; u16 u; } v; v.h = (_Float16)x; return v.u;
}
__device__ inline h2 u2h2(unsigned u) {
  union { unsigned u; h2 h; } v; v.u = u; return v.h;
}
__device__ inline float dot2(h2 a, h2 b, float c) {
#if __has_builtin(__builtin_amdgcn_fdot2)
  return __builtin_amdgcn_fdot2(a, b, c, false);
#else
  return c + (float)a[0] * (float)b[0] + (float)a[1] * (float)b[1];
#endif
}

// ============================ CSR build ============================
__global__ __launch_bounds__(256) void k_zero_i32(int* __restrict__ p, int n) {
  int i = blockIdx.x * 256 + threadIdx.x;
  if (i < n) p[i] = 0;
}
__global__ __launch_bounds__(256) void k_hist(const int* __restrict__ idx, int n,
                                              int* __restrict__ cnt) {
  int i = blockIdx.x * 256 + threadIdx.x;
  if (i < n) atomicAdd(&cnt[idx[i]], 1);
}
__global__ __launch_bounds__(1024) void k_exscan(const int* __restrict__ in, int n,
                                                 int* __restrict__ out) {
  __shared__ int buf[1024];
  __shared__ int carry_s;
  if (threadIdx.x == 0) carry_s = 0;
  __syncthreads();
  for (int base = 0; base < n; base += 1024) {
    int i = base + (int)threadIdx.x;
    int v = (i < n) ? in[i] : 0;
    buf[threadIdx.x] = v;
    __syncthreads();
    int x = v;
    for (int off = 1; off < 1024; off <<= 1) {
      int t = (threadIdx.x >= (unsigned)off) ? buf[threadIdx.x - off] : 0;
      __syncthreads();
      x += t;
      buf[threadIdx.x] = x;
      __syncthreads();
    }
    int carry = carry_s;
    if (i < n) out[i] = carry + x - v;
    __syncthreads();
    if (threadIdx.x == 1023) carry_s = carry + buf[1023];
    __syncthreads();
  }
  if (threadIdx.x == 0) out[n] = carry_s;
}
__global__ __launch_bounds__(256) void k_copy_i32(const int* __restrict__ a,
                                                  int* __restrict__ b, int n) {
  int i = blockIdx.x * 256 + threadIdx.x;
  if (i < n) b[i] = a[i];
}
__global__ __launch_bounds__(256) void k_scatter_edges(const int* __restrict__ src,
                                                       const int* __restrict__ dst, int nE,
                                                       int* __restrict__ cur,
                                                       int* __restrict__ slots) {
  int e = blockIdx.x * 256 + threadIdx.x;
  if (e < nE) {
    int p = atomicAdd(&cur[dst[e]], 1);
    slots[p] = src[e];
  }
}
__global__ __launch_bounds__(256) void k_scatter_nodes(const int* __restrict__ cl, int n,
                                                       int* __restrict__ cur,
                                                       int* __restrict__ slots) {
  int i = blockIdx.x * 256 + threadIdx.x;
  if (i < n) {
    int p = atomicAdd(&cur[cl[i]], 1);
    slots[p] = i;
  }
}

// ============================ weight pack (hi+lo planes) ============================
__global__ __launch_bounds__(256) void k_pack(const float* __restrict__ W,
                                              const float* __restrict__ u,
                                              const float* __restrict__ sW,
                                              u16* __restrict__ Bph, u16* __restrict__ Bpl,
                                              int C, int K1, int K2, int Kpad, int Mld) {
  int idx = blockIdx.x * 256 + threadIdx.x;
  if (idx >= Mld * Kpad) return;
  int col = idx / Kpad, kp = idx - col * Kpad;
  int ksrc = -1;
  if (kp < K1) ksrc = kp;
  else if (kp >= HALF && kp - HALF < K2) ksrc = K1 + (kp - HALF);
  float v = 0.f;
  if (ksrc >= 0) {
    if (col < 4 * C) {
      int c = col >> 2, h = col & 3;
      v = W[(size_t)ksrc * 4 * C + h * C + c];
    } else if (col < 4 * C + 4) {
      v = u[(size_t)ksrc * 4 + (col - 4 * C)];
    } else if (sW && col < 5 * C + 4) {
      v = sW[(size_t)ksrc * C + (col - 4 * C - 4)];
    }
  }
  u16 hi = f2b(v);
  Bph[idx] = hi;
  Bpl[idx] = f2b(v - b2f(hi));
}

// 10 identical 140->140 packs in one launch. Bps_all: per layer 2*576*160 u16 (h then l).
__global__ __launch_bounds__(256) void k_pack10(const float* __restrict__ Ws,
                                                const float* __restrict__ us,
                                                u16* __restrict__ Bps_all) {
  const int per = 576 * 160;
  int idx = blockIdx.x * 256 + threadIdx.x;
  if (idx >= 10 * per) return;
  int layer = idx / per, r = idx - layer * per;
  int col = r / 160, kp = r - col * 160;
  float v = 0.f;
  if (kp < CC) {
    const float* W = Ws + (size_t)layer * CC * 4 * CC;
    const float* u = us + (size_t)layer * CC * 4;
    if (col < 4 * CC) {
      int c = col >> 2, h = col & 3;
      v = W[(size_t)kp * 4 * CC + h * CC + c];
    } else if (col < 4 * CC + 4) {
      v = u[(size_t)kp * 4 + (col - 4 * CC)];
    }
  }
  u16 hi = f2b(v);
  u16* base = Bps_all + (size_t)layer * 2 * per;
  base[r] = hi;
  base[per + r] = f2b(v - b2f(hi));
}

__global__ __launch_bounds__(256) void k_pack_x(const float* __restrict__ x,
                                                u16* __restrict__ xh, u16* __restrict__ xl,
                                                int n) {
  int idx = blockIdx.x * 256 + threadIdx.x;
  if (idx >= n * 32) return;
  int i = idx >> 5, c = idx & 31;
  float v = (c < 4) ? x[(size_t)i * 4 + c] : 0.f;
  u16 hi = f2b(v);
  xh[idx] = hi;
  xl[idx] = f2b(v - b2f(hi));
}

// ============================ split-bf16 MFMA GEMM, split output ============================
// (Ah+Al)[N][K] @ (Bh+Bl)^T (AlBl dropped). Output by column:
//   gc < yEnd            -> Gy f16, row-stride yEnd
//   yEnd <= gc < yEnd+4  -> Gl f32, row-stride 4   (attention logits)
//   yEnd+4 <= gc < +Cs   -> Gs f32, row-stride Cs  (GEMM skip)
__global__ __launch_bounds__(256) void k_gemm_mfma(
    const u16* __restrict__ A1h, const u16* __restrict__ A1l,
    const u16* __restrict__ A2h, const u16* __restrict__ A2l,
    const int* __restrict__ amap,
    const u16* __restrict__ Bph, const u16* __restrict__ Bpl,
    u16* __restrict__ Gy, float* __restrict__ Gl, float* __restrict__ Gs,
    int yEnd, int Cs, int N, int Kpad, int lda1) {
  __shared__ __align__(16) u16 Ash[128 * 32];
  __shared__ __align__(16) u16 Asl[128 * 32];
  __shared__ __align__(16) u16 Bsh[64 * 32];
  __shared__ __align__(16) u16 Bsl[64 * 32];
  const int tid = threadIdx.x;
  const int row0 = blockIdx.y * 128, col0 = blockIdx.x * 64;
  const int w = tid >> 6, lane = tid & 63;
  const int wm = w >> 1, wn = w & 1;
  const int arow = lane & 15, chunk = lane >> 4;
  const int swz = chunk ^ (arow & 3);
  f32x4 acc[4][2];
#pragma unroll
  for (int i = 0; i < 4; ++i)
#pragma unroll
    for (int j = 0; j < 2; ++j) acc[i][j] = (f32x4){0.f, 0.f, 0.f, 0.f};
  const int sar = tid >> 1;
  const int sak = (tid & 1) * 16;
  const int sbc = tid >> 2;
  const int sbk = (tid & 3) * 8;
  for (int k0 = 0; k0 < Kpad; k0 += 32) {
    {
      int gr = row0 + sar;
      short8 v0h = {0,0,0,0,0,0,0,0}, v1h = v0h, v0l = v0h, v1l = v0h;
      if (gr < N) {
        int kp0 = k0 + sak;
        const u16 *bh_, *bl_;
        int rr, kk, ld;
        if (A2h && kp0 >= HALF) {
          bh_ = A2h; bl_ = A2l; rr = gr; kk = kp0 - HALF; ld = HALF;
        } else {
          bh_ = A1h; bl_ = A1l; rr = amap ? amap[gr] : gr; kk = kp0; ld = lda1;
        }
        const u16* ph = bh_ + (size_t)rr * ld + kk;
        const u16* pl = bl_ + (size_t)rr * ld + kk;
        v0h = *(const short8*)(ph);
        v1h = *(const short8*)(ph + 8);
        v0l = *(const short8*)(pl);
        v1l = *(const short8*)(pl + 8);
      }
      int c0 = sak >> 3, sw = sar & 3;
      *(short8*)(Ash + sar * 32 + ((c0 ^ sw) << 3)) = v0h;
      *(short8*)(Ash + sar * 32 + (((c0 + 1) ^ sw) << 3)) = v1h;
      *(short8*)(Asl + sar * 32 + ((c0 ^ sw) << 3)) = v0l;
      *(short8*)(Asl + sar * 32 + (((c0 + 1) ^ sw) << 3)) = v1l;
    }
    {
      int gc = col0 + sbc;
      short8 vh = *(const short8*)(Bph + (size_t)gc * Kpad + k0 + sbk);
      short8 vl = *(const short8*)(Bpl + (size_t)gc * Kpad + k0 + sbk);
      int c = sbk >> 3, sw = sbc & 3;
      *(short8*)(Bsh + sbc * 32 + ((c ^ sw) << 3)) = vh;
      *(short8*)(Bsl + sbc * 32 + ((c ^ sw) << 3)) = vl;
    }
    __syncthreads();
    short8 bh[2], bl[2], ah[4], al[4];
#pragma unroll
    for (int ni = 0; ni < 2; ++ni) {
      int col = wn * 32 + ni * 16 + arow;
      bh[ni] = *(const short8*)(Bsh + col * 32 + (swz << 3));
      bl[ni] = *(const short8*)(Bsl + col * 32 + (swz << 3));
    }
#pragma unroll
    for (int mi = 0; mi < 4; ++mi) {
      int r = wm * 64 + mi * 16 + arow;
      ah[mi] = *(const short8*)(Ash + r * 32 + (swz << 3));
      al[mi] = *(const short8*)(Asl + r * 32 + (swz << 3));
    }
#pragma unroll
    for (int mi = 0; mi < 4; ++mi)
#pragma unroll
      for (int ni = 0; ni < 2; ++ni)
        acc[mi][ni] = __builtin_amdgcn_mfma_f32_16x16x32_bf16(ah[mi], bh[ni], acc[mi][ni], 0, 0, 0);
#pragma unroll
    for (int mi = 0; mi < 4; ++mi)
#pragma unroll
      for (int ni = 0; ni < 2; ++ni)
        acc[mi][ni] = __builtin_amdgcn_mfma_f32_16x16x32_bf16(ah[mi], bl[ni], acc[mi][ni], 0, 0, 0);
#pragma unroll
    for (int mi = 0; mi < 4; ++mi)
#pragma unroll
      for (int ni = 0; ni < 2; ++ni)
        acc[mi][ni] = __builtin_amdgcn_mfma_f32_16x16x32_bf16(al[mi], bh[ni], acc[mi][ni], 0, 0, 0);
    __syncthreads();
  }
  const int crow = (lane >> 4) * 4, ccol = lane & 15;
#pragma unroll
  for (int mi = 0; mi < 4; ++mi) {
    int gr0 = row0 + wm * 64 + mi * 16 + crow;
#pragma unroll
    for (int ni = 0; ni < 2; ++ni) {
      int gc = col0 + wn * 32 + ni * 16 + ccol;
#pragma unroll
      for (int j = 0; j < 4; ++j) {
        int gr = gr0 + j;
        if (gr >= N) continue;
        float v = acc[mi][ni][j];
        if (gc < yEnd) Gy[(size_t)gr * yEnd + gc] = f2h(v);
        else if (gc < yEnd + 4) Gl[(size_t)gr * 4 + (gc - yEnd)] = v;
        else if (gc < yEnd + 4 + Cs) Gs[(size_t)gr * Cs + (gc - yEnd - 4)] = v;
      }
    }
  }
}

// ============================ fused FeaSt agg + LN + skip + relu ============================
// Gy f16 (n,560) head-minor; Gl f32 (n,4); distributed softmax + fdot2 inner loop
__global__ __launch_bounds__(256) void k_agg(
    const u16* __restrict__ Gy, const float* __restrict__ Gl,
    const float* __restrict__ cv, const float* __restrict__ bias,
    const float* __restrict__ g, const float* __restrict__ be,
    const u16* __restrict__ inH, const u16* __restrict__ inL,  // identity skip (or null)
    const float* __restrict__ Gs, const float* __restrict__ sb, // GEMM skip
    const int* __restrict__ rp, const int* __restrict__ sl,
    u16* __restrict__ outH, u16* __restrict__ outL, int n, int relu) {
  int wid = blockIdx.x * 4 + ((int)threadIdx.x >> 6);
  int lane = threadIdx.x & 63;
  if (wid >= n) return;
  float4 la = *(const float4*)(Gl + (size_t)wid * 4);
  float d0 = cv[0] - la.x, d1 = cv[1] - la.y;
  float d2 = cv[2] - la.z, d3 = cv[3] - la.w;
  int eb = rp[wid], ee = rp[wid + 1];
  const int c0 = lane, c1 = lane + 64, c2 = lane + 128;
  const bool h2v = c2 < CC;
  float acc0 = 0.f, acc1 = 0.f, acc2 = 0.f;
  for (int base = eb; base < ee; base += 64) {
    int m = min(ee - base, 64);
    // phase 1: lane j computes softmax weights for edge base+j, packs to 2 x f16x2
    int sreg = 0;
    int q01 = 0, q23 = 0;
    if (lane < m) {
      sreg = sl[base + lane];
      float4 lg = *(const float4*)(Gl + (size_t)sreg * 4);
      float t0 = lg.x + d0, t1 = lg.y + d1, t2 = lg.z + d2, t3 = lg.w + d3;
      float mx = fmaxf(fmaxf(t0, t1), fmaxf(t2, t3));
      float q0 = __expf(t0 - mx), q1 = __expf(t1 - mx);
      float q2 = __expf(t2 - mx), q3 = __expf(t3 - mx);
      float qi = 1.f / (q0 + q1 + q2 + q3);
      q01 = (int)((unsigned)f2h(q0 * qi) | ((unsigned)f2h(q1 * qi) << 16));
      q23 = (int)((unsigned)f2h(q2 * qi) | ((unsigned)f2h(q3 * qi) << 16));
    }
    // phase 2: broadcast edge j's (src, q) to all lanes; gather + dot2
#pragma unroll 2
    for (int j = 0; j < m; ++j) {
      int s = __shfl(sreg, j);
      h2 p01 = u2h2((unsigned)__shfl(q01, j));
      h2 p23 = u2h2((unsigned)__shfl(q23, j));
      const u16* gy = Gy + (size_t)s * 560;
      uint2 y0 = *(const uint2*)(gy + (c0 << 2));
      acc0 = dot2(u2h2(y0.x), p01, acc0);
      acc0 = dot2(u2h2(y0.y), p23, acc0);
      uint2 y1 = *(const uint2*)(gy + (c1 << 2));
      acc1 = dot2(u2h2(y1.x), p01, acc1);
      acc1 = dot2(u2h2(y1.y), p23, acc1);
      if (h2v) {
        uint2 y2 = *(const uint2*)(gy + (c2 << 2));
        acc2 = dot2(u2h2(y2.x), p01, acc2);
        acc2 = dot2(u2h2(y2.y), p23, acc2);
      }
    }
  }
  int cnt = ee - eb;
  float inv = 1.f / (float)(cnt > 1 ? cnt : 1);
  float v0 = acc0 * inv + bias[c0];
  float v1 = acc1 * inv + bias[c1];
  float v2 = h2v ? acc2 * inv + bias[c2] : 0.f;
  if (g) {
    float s1 = v0 + v1 + v2;
    float s2 = v0 * v0 + v1 * v1 + v2 * v2;
#pragma unroll
    for (int off = 32; off > 0; off >>= 1) {
      s1 += __shfl_xor(s1, off);
      s2 += __shfl_xor(s2, off);
    }
    float mu = s1 * (1.0f / CC);
    float var = s2 * (1.0f / CC) - mu * mu;
    float r = rsqrtf(var + 1e-5f);
    v0 = (v0 - mu) * r * g[c0] + be[c0];
    v1 = (v1 - mu) * r * g[c1] + be[c1];
    if (h2v) v2 = (v2 - mu) * r * g[c2] + be[c2];
  }
  if (inH) {
    const u16* ih = inH + (size_t)wid * HALF;
    const u16* il = inL + (size_t)wid * HALF;
    v0 += b2f(ih[c0]) + b2f(il[c0]);
    v1 += b2f(ih[c1]) + b2f(il[c1]);
    if (h2v) v2 += b2f(ih[c2]) + b2f(il[c2]);
  } else {
    const float* gsr = Gs + (size_t)wid * CC;
    v0 += gsr[c0] + sb[c0];
    v1 += gsr[c1] + sb[c1];
    if (h2v) v2 += gsr[c2] + sb[c2];
  }
  if (relu) {
    v0 = fmaxf(v0, 0.f); v1 = fmaxf(v1, 0.f); v2 = fmaxf(v2, 0.f);
  }
  u16* oh = outH + (size_t)wid * HALF;
  u16* ol = outL + (size_t)wid * HALF;
  u16 h0 = f2b(v0); oh[c0] = h0; ol[c0] = f2b(v0 - b2f(h0));
  u16 h1 = f2b(v1); oh[c1] = h1; ol[c1] = f2b(v1 - b2f(h1));
  if (h2v) {
    u16 h2_ = f2b(v2); oh[c2] = h2_; ol[c2] = f2b(v2 - b2f(h2_));
  } else if (c2 < HALF) {
    oh[c2] = 0; ol[c2] = 0;
  }
}

// conv06: Gy f16 (n,4) = Y heads; Gl f32 logits; Gs f32 (n,1) skip
__global__ __launch_bounds__(256) void k_out(
    const u16* __restrict__ Gy, const float* __restrict__ Gl,
    const float* __restrict__ cv, const float* __restrict__ bo,
    const float* __restrict__ Gs, const float* __restrict__ sbo,
    const int* __restrict__ rp, const int* __restrict__ sl,
    float* __restrict__ out, int n) {
  int wid = blockIdx.x * 4 + ((int)threadIdx.x >> 6);
  int lane = threadIdx.x & 63;
  if (wid >= n) return;
  float4 la = *(const float4*)(Gl + (size_t)wid * 4);
  float d0 = cv[0] - la.x, d1 = cv[1] - la.y;
  float d2 = cv[2] - la.z, d3 = cv[3] - la.w;
  int eb = rp[wid], ee = rp[wid + 1];
  float part = 0.f;
  for (int e = eb + lane; e < ee; e += 64) {
    int s = sl[e];
    float4 lg = *(const float4*)(Gl + (size_t)s * 4);
    float t0 = lg.x + d0, t1 = lg.y + d1, t2 = lg.z + d2, t3 = lg.w + d3;
    float m = fmaxf(fmaxf(t0, t1), fmaxf(t2, t3));
    float q0 = __expf(t0 - m), q1 = __expf(t1 - m), q2 = __expf(t2 - m), q3 = __expf(t3 - m);
    float qi = 1.f / (q0 + q1 + q2 + q3);
    uint2 y = *(const uint2*)(Gy + (size_t)s * 4);
    h2 y01 = u2h2(y.x), y23 = u2h2(y.y);
    part += (q0 * (float)y01[0] + q1 * (float)y01[1] +
             q2 * (float)y23[0] + q3 * (float)y23[1]) * qi;
  }
#pragma unroll
  for (int off = 32; off > 0; off >>= 1) part += __shfl_xor(part, off);
  if (lane == 0) {
    int cnt = ee - eb;
    out[wid] = part / (float)(cnt > 1 ? cnt : 1) + bo[0] + Gs[wid] + sbo[0];
  }
}

// ============================ pool (split planes in/out) ============================
__global__ __launch_bounds__(256) void k_pool(const u16* __restrict__ inH,
                                              const u16* __restrict__ inL,
                                              const int* __restrict__ rp,
                                              const int* __restrict__ sl,
                                              u16* __restrict__ outH,
                                              u16* __restrict__ outL, int nseg) {
  int wid = blockIdx.x * 4 + ((int)threadIdx.x >> 6);
  int lane = threadIdx.x & 63;
  if (wid >= nseg) return;
  int a = rp[wid], b = rp[wid + 1];
  const int c0 = lane, c1 = lane + 64, c2 = lane + 128;
  const bool h2v = c2 < CC;
  float acc0 = 0.f, acc1 = 0.f, acc2 = 0.f;
  for (int s = a; s < b; ++s) {
    size_t off = (size_t)sl[s] * HALF;
    acc0 += b2f(inH[off + c0]) + b2f(inL[off + c0]);
    acc1 += b2f(inH[off + c1]) + b2f(inL[off + c1]);
    if (h2v) acc2 += b2f(inH[off + c2]) + b2f(inL[off + c2]);
  }
  int cnt = b - a;
  float inv = 1.f / (float)(cnt > 1 ? cnt : 1);
  float v0 = acc0 * inv, v1 = acc1 * inv, v2 = acc2 * inv;
  u16* oh = outH + (size_t)wid * HALF;
  u16* ol = outL + (size_t)wid * HALF;
  u16 h0 = f2b(v0); oh[c0] = h0; ol[c0] = f2b(v0 - b2f(h0));
  u16 h1 = f2b(v1); oh[c1] = h1; ol[c1] = f2b(v1 - b2f(h1));
  if (h2v) {
    u16 h2_ = f2b(v2); oh[c2] = h2_; ol[c2] = f2b(v2 - b2f(h2_));
  } else if (c2 < HALF) {
    oh[c2] = 0; ol[c2] = 0;
  }
}

// ============================ host ============================
extern "C" void kernel_launch(void* const* d_in, const int* in_sizes, int n_in,
                              void* d_out, int out_size, void* d_ws, size_t ws_size,
                              hipStream_t stream) {
  (void)n_in; (void)out_size;
  const float* x    = (const float*)d_in[0];
  const int*   e0   = (const int*)d_in[1];
  const int*   e1   = (const int*)d_in[2];
  const int*   e2   = (const int*)d_in[3];
  const int*   cl1  = (const int*)d_in[4];
  const int*   cl2  = (const int*)d_in[5];
  const float* W01  = (const float*)d_in[9];
  const float* u01  = (const float*)d_in[10];
  const float* c01  = (const float*)d_in[11];
  const float* b01  = (const float*)d_in[12];
  const float* sW01 = (const float*)d_in[13];
  const float* sb01 = (const float*)d_in[14];
  const float* g01  = (const float*)d_in[15];
  const float* be01 = (const float*)d_in[16];
  const float* Ws   = (const float*)d_in[17];
  const float* us   = (const float*)d_in[18];
  const float* cs   = (const float*)d_in[19];
  const float* bs   = (const float*)d_in[20];
  const float* gs   = (const float*)d_in[21];
  const float* bes  = (const float*)d_in[22];
  const float* Wc   = (const float*)d_in[23];
  const float* uc   = (const float*)d_in[24];
  const float* cc   = (const float*)d_in[25];
  const float* bc   = (const float*)d_in[26];
  const float* sWc  = (const float*)d_in[27];
  const float* sbc  = (const float*)d_in[28];
  const float* gc   = (const float*)d_in[29];
  const float* bec  = (const float*)d_in[30];
  const float* Wo   = (const float*)d_in[31];
  const float* uo   = (const float*)d_in[32];
  const float* co   = (const float*)d_in[33];
  const float* bo   = (const float*)d_in[34];
  const float* sWo  = (const float*)d_in[35];
  const float* sbo  = (const float*)d_in[36];

  const int N0 = in_sizes[0] / 4;
  const int nE0 = in_sizes[1] / 2;
  const int nE1 = in_sizes[2] / 2;
  const int nE2 = in_sizes[3] / 2;
  const int N1 = 5000, N2 = 1250;

  // ---- workspace layout ----
  float* fp = (float*)d_ws;
  auto alloc_f = [&](size_t n) { n = (n + 15) & ~(size_t)15; float* p = fp; fp += n; return p; };
  auto alloc_h = [&](size_t n) { return (u16*)alloc_f((n + 1) / 2); };
  u16*   Gy = alloc_h((size_t)N0 * 560);
  float* Gl = alloc_f((size_t)N0 * 4);
  float* Gs = alloc_f((size_t)N0 * CC);
  u16* a0Ah = alloc_h((size_t)N0 * HALF);
  u16* a0Al = alloc_h((size_t)N0 * HALF);
  u16* a0Bh = alloc_h((size_t)N0 * HALF);
  u16* a0Bl = alloc_h((size_t)N0 * HALF);
  u16* a1Ah = alloc_h((size_t)N1 * HALF);
  u16* a1Al = alloc_h((size_t)N1 * HALF);
  u16* a1Bh = alloc_h((size_t)N1 * HALF);
  u16* a1Bl = alloc_h((size_t)N1 * HALF);
  u16* a2Ah = alloc_h((size_t)N2 * HALF);
  u16* a2Al = alloc_h((size_t)N2 * HALF);
  u16* a2Bh = alloc_h((size_t)N2 * HALF);
  u16* a2Bl = alloc_h((size_t)N2 * HALF);
  u16* xbh  = alloc_h((size_t)N0 * 32);
  u16* xbl  = alloc_h((size_t)N0 * 32);
  u16* Bp01h = alloc_h((size_t)704 * 32);
  u16* Bp01l = alloc_h((size_t)704 * 32);
  const size_t PER10 = (size_t)576 * 160;
  u16* Bps_all = alloc_h(10 * 2 * PER10);   // per layer: [h plane][l plane]
  u16 *Bpsh[10], *Bpsl[10];
  for (int i = 0; i < 10; ++i) {
    Bpsh[i] = Bps_all + (size_t)i * 2 * PER10;
    Bpsl[i] = Bpsh[i] + PER10;
  }
  u16* Bpc0h = alloc_h((size_t)704 * 320);
  u16* Bpc0l = alloc_h((size_t)704 * 320);
  u16* Bpc1h = alloc_h((size_t)704 * 320);
  u16* Bpc1l = alloc_h((size_t)704 * 320);
  u16* Bpoh  = alloc_h((size_t)64 * 160);
  u16* Bpol  = alloc_h((size_t)64 * 160);
  int* ipb = (int*)fp;
  auto alloc_i = [&](size_t n) { int* p = ipb; ipb += n; return p; };
  int* rp0  = alloc_i(N0 + 1);
  int* sl0  = alloc_i(nE0);
  int* rp1  = alloc_i(N1 + 1);
  int* sl1  = alloc_i(nE1);
  int* rp2  = alloc_i(N2 + 1);
  int* sl2  = alloc_i(nE2);
  int* rpc1 = alloc_i(N1 + 1);
  int* slc1 = alloc_i(N0);
  int* rpc2 = alloc_i(N2 + 1);
  int* slc2 = alloc_i(N1);
  int* cur  = alloc_i(N0 + 1);
  if ((size_t)((char*)ipb - (char*)d_ws) > ws_size) return;

  auto cdiv = [](int a, int b) { return (a + b - 1) / b; };

  // ---- CSR builds ----
  auto build_edges = [&](const int* ei, int nE, int nN, int* rp, int* sl) {
    k_zero_i32<<<cdiv(nN, 256), 256, 0, stream>>>(cur, nN);
    k_hist<<<cdiv(nE, 256), 256, 0, stream>>>(ei + nE, nE, cur);
    k_exscan<<<1, 1024, 0, stream>>>(cur, nN, rp);
    k_copy_i32<<<cdiv(nN, 256), 256, 0, stream>>>(rp, cur, nN);
    k_scatter_edges<<<cdiv(nE, 256), 256, 0, stream>>>(ei, ei + nE, nE, cur, sl);
  };
  auto build_cl = [&](const int* cl, int nSrc, int nN, int* rp, int* sl) {
    k_zero_i32<<<cdiv(nN, 256), 256, 0, stream>>>(cur, nN);
    k_hist<<<cdiv(nSrc, 256), 256, 0, stream>>>(cl, nSrc, cur);
    k_exscan<<<1, 1024, 0, stream>>>(cur, nN, rp);
    k_copy_i32<<<cdiv(nN, 256), 256, 0, stream>>>(rp, cur, nN);
    k_scatter_nodes<<<cdiv(nSrc, 256), 256, 0, stream>>>(cl, nSrc, cur, sl);
  };
  build_edges(e0, nE0, N0, rp0, sl0);
  build_edges(e1, nE1, N1, rp1, sl1);
  build_edges(e2, nE2, N2, rp2, sl2);
  build_cl(cl1, N0, N1, rpc1, slc1);
  build_cl(cl2, N1, N2, rpc2, slc2);

  // ---- weight packing ----
  auto pack = [&](const float* W, const float* u, const float* sW, u16* Bh, u16* Bl,
                  int C, int K1, int K2, int Kpad, int Mld) {
    int tot = Mld * Kpad;
    k_pack<<<cdiv(tot, 256), 256, 0, stream>>>(W, u, sW, Bh, Bl, C, K1, K2, Kpad, Mld);
  };
  pack(W01, u01, sW01, Bp01h, Bp01l, CC, 4, 0, 32, 704);
  k_pack10<<<cdiv(10 * (int)PER10, 256), 256, 0, stream>>>(Ws, us, Bps_all);
  pack(Wc, uc, sWc, Bpc0h, Bpc0l, CC, CC, CC, 320, 704);
  pack(Wc + (size_t)2 * CC * HH * CC, uc + (size_t)2 * CC * HH, sWc + (size_t)2 * CC * CC,
       Bpc1h, Bpc1l, CC, CC, CC, 320, 704);
  pack(Wo, uo, sWo, Bpoh, Bpol, 1, CC, 0, 160, 64);
  k_pack_x<<<cdiv(N0 * 32, 256), 256, 0, stream>>>(x, xbh, xbl, N0);

  // conv driver
  auto do_conv = [&](const u16* A1h, const u16* A1l, const u16* A2h, const u16* A2l,
                     const int* amap, int Kpad, int lda1, const u16* Bh, const u16* Bl,
                     int Mld, bool hasSkip, int n, const int* rp, const int* sl,
                     const float* cp, const float* bp, const float* gp, const float* bep,
                     const u16* skipH, const u16* skipL, const float* sbp,
                     u16* outH, u16* outL) {
    dim3 grid(Mld / 64, cdiv(n, 128));
    k_gemm_mfma<<<grid, 256, 0, stream>>>(A1h, A1l, A2h, A2l, amap, Bh, Bl,
                                          Gy, Gl, Gs, 560, hasSkip ? CC : 0, n, Kpad, lda1);
    k_agg<<<cdiv(n, 4), 256, 0, stream>>>(Gy, Gl, cp, bp, gp, bep, skipH, skipL, Gs, sbp,
                                          rp, sl, outH, outL, n, 1);
  };

  auto ci  = [&](int i) { return cs + (size_t)i * HH; };
  auto bi  = [&](int i) { return bs + (size_t)i * CC; };
  auto gi  = [&](int i) { return gs + (size_t)i * CC; };
  auto bei = [&](int i) { return bes + (size_t)i * CC; };

  // conv01: K=4 (padded 32), GEMM skip
  do_conv(xbh, xbl, nullptr, nullptr, nullptr, 32, 32, Bp01h, Bp01l, 704, true, N0, rp0, sl0,
          c01, b01, g01, be01, nullptr, nullptr, sb01, a0Ah, a0Al);
  // conv02 (identity skip) -> copy0 = a0B
  do_conv(a0Ah, a0Al, nullptr, nullptr, nullptr, 160, HALF, Bpsh[0], Bpsl[0], 576, false,
          N0, rp0, sl0, ci(0), bi(0), gi(0), bei(0), a0Ah, a0Al, nullptr, a0Bh, a0Bl);
  // pool1
  k_pool<<<cdiv(N1, 4), 256, 0, stream>>>(a0Bh, a0Bl, rpc1, slc1, a1Ah, a1Al, N1);
  // conv11, conv12 (copy1 = a1A after conv12)
  do_conv(a1Ah, a1Al, nullptr, nullptr, nullptr, 160, HALF, Bpsh[1], Bpsl[1], 576, false,
          N1, rp1, sl1, ci(1), bi(1), gi(1), bei(1), a1Ah, a1Al, nullptr, a1Bh, a1Bl);
  do_conv(a1Bh, a1Bl, nullptr, nullptr, nullptr, 160, HALF, Bpsh[2], Bpsl[2], 576, false,
          N1, rp1, sl1, ci(2), bi(2), gi(2), bei(2), a1Bh, a1Bl, nullptr, a1Ah, a1Al);
  // pool2
  k_pool<<<cdiv(N2, 4), 256, 0, stream>>>(a1Ah, a1Al, rpc2, slc2, a2Ah, a2Al, N2);
  // conv21, conv22
  do_conv(a2Ah, a2Al, nullptr, nullptr, nullptr, 160, HALF, Bpsh[3], Bpsl[3], 576, false,
          N2, rp2, sl2, ci(3), bi(3), gi(3), bei(3), a2Ah, a2Al, nullptr, a2Bh, a2Bl);
  do_conv(a2Bh, a2Bl, nullptr, nullptr, nullptr, 160, HALF, Bpsh[4], Bpsl[4], 576, false,
          N2, rp2, sl2, ci(4), bi(4), gi(4), bei(4), a2Bh, a2Bl, nullptr, a2Ah, a2Al);
  // conv13 on [unpool2(a2A) | a1A], GEMM skip
  do_conv(a2Ah, a2Al, a1Ah, a1Al, cl2, 320, HALF, Bpc0h, Bpc0l, 704, true, N1, rp1, sl1,
          cc, bc, gc, bec, nullptr, nullptr, sbc, a1Bh, a1Bl);
  // conv14, conv15, conv16
  do_conv(a1Bh, a1Bl, nullptr, nullptr, nullptr, 160, HALF, Bpsh[5], Bpsl[5], 576, false,
          N1, rp1, sl1, ci(5), bi(5), gi(5), bei(5), a1Bh, a1Bl, nullptr, a1Ah, a1Al);
  do_conv(a1Ah, a1Al, nullptr, nullptr, nullptr, 160, HALF, Bpsh[6], Bpsl[6], 576, false,
          N1, rp1, sl1, ci(6), bi(6), gi(6), bei(6), a1Ah, a1Al, nullptr, a1Bh, a1Bl);
  do_conv(a1Bh, a1Bl, nullptr, nullptr, nullptr, 160, HALF, Bpsh[7], Bpsl[7], 576, false,
          N1, rp1, sl1, ci(7), bi(7), gi(7), bei(7), a1Bh, a1Bl, nullptr, a1Ah, a1Al);
  // conv03 on [unpool1(a1A) | a0B], GEMM skip
  do_conv(a1Ah, a1Al, a0Bh, a0Bl, cl1, 320, HALF, Bpc1h, Bpc1l, 704, true, N0, rp0, sl0,
          cc + HH, bc + CC, gc + CC, bec + CC, nullptr, nullptr, sbc + CC, a0Ah, a0Al);
  // conv04, conv05
  do_conv(a0Ah, a0Al, nullptr, nullptr, nullptr, 160, HALF, Bpsh[8], Bpsl[8], 576, false,
          N0, rp0, sl0, ci(8), bi(8), gi(8), bei(8), a0Ah, a0Al, nullptr, a0Bh, a0Bl);
  do_conv(a0Bh, a0Bl, nullptr, nullptr, nullptr, 160, HALF, Bpsh[9], Bpsl[9], 576, false,
          N0, rp0, sl0, ci(9), bi(9), gi(9), bei(9), a0Bh, a0Bl, nullptr, a0Ah, a0Al);
  // conv06: 140 -> 1   (Gy stride 4, logits in Gl, skip in Gs col 0)
  {
    dim3 grid(1, cdiv(N0, 128));
    k_gemm_mfma<<<grid, 256, 0, stream>>>(a0Ah, a0Al, nullptr, nullptr, nullptr,
                                          Bpoh, Bpol, Gy, Gl, Gs, 4, 1, N0, 160, HALF);
    k_out<<<cdiv(N0, 4), 256, 0, stream>>>(Gy, Gl, co, bo, Gs, sbo, rp0, sl0, (float*)d_out, N0);
  }
}

// Round 7
// 713.191 us; speedup vs baseline: 3.1498x; 1.2307x over previous
//
#include <hip/hip_runtime.h>
#include <math.h>

#define HH 4
#define CC 140
#define HALF 160   // padded K of one concat half / one plain input

typedef __attribute__((ext_vector_type(8))) short short8;
typedef __attribute__((ext_vector_type(8))) _Float16 half8;
typedef __attribute__((ext_vector_type(4))) float f32x4;
typedef __attribute__((ext_vector_type(2))) _Float16 h2;
typedef unsigned short u16;

__device__ inline u16 f2h(float x) {
  union { _Float16 h; u16 u; } v; v.h = (_Float16)x; return v.u;
}
__device__ inline float h2f(u16 u) {
  union { _Float16 h; u16 u; } v; v.u = u; return (float)v.h;
}
__device__ inline h2 u2h2(unsigned u) {
  union { unsigned u; h2 h; } v; v.u = u; return v.h;
}
__device__ inline float dot2(h2 a, h2 b, float c) {
#if __has_builtin(__builtin_amdgcn_fdot2)
  return __builtin_amdgcn_fdot2(a, b, c, false);
#else
  return c + (float)a[0] * (float)b[0] + (float)a[1] * (float)b[1];
#endif
}

// ============================ fused CSR build (4 launches) ============================
__global__ __launch_bounds__(256) void k_zero_i32(int* __restrict__ p, int n) {
  int i = blockIdx.x * 256 + threadIdx.x;
  if (i < n) p[i] = 0;
}
// one launch: histogram all 3 edge lists (dst row) + 2 cluster maps
__global__ __launch_bounds__(256) void k_hist_all(
    const int* __restrict__ e0, int nE0, const int* __restrict__ e1, int nE1,
    const int* __restrict__ e2, int nE2, const int* __restrict__ cl1, int n0,
    const int* __restrict__ cl2, int n1,
    int* __restrict__ c0, int* __restrict__ c1, int* __restrict__ c2,
    int* __restrict__ c3, int* __restrict__ c4) {
  int j = blockIdx.x * 256 + threadIdx.x;
  if (j < nE0) { atomicAdd(&c0[e0[nE0 + j]], 1); return; }
  j -= nE0;
  if (j < nE1) { atomicAdd(&c1[e1[nE1 + j]], 1); return; }
  j -= nE1;
  if (j < nE2) { atomicAdd(&c2[e2[nE2 + j]], 1); return; }
  j -= nE2;
  if (j < n0) { atomicAdd(&c3[cl1[j]], 1); return; }
  j -= n0;
  if (j < n1) { atomicAdd(&c4[cl2[j]], 1); }
}
// 5 blocks; block b: exclusive-scan cnt[b] -> rp[b], and cnt[b] <- prefix (scatter cursors)
__global__ __launch_bounds__(1024) void k_exscan5(
    int* __restrict__ c0, int n0, int* __restrict__ r0,
    int* __restrict__ c1, int n1, int* __restrict__ r1,
    int* __restrict__ c2, int n2, int* __restrict__ r2,
    int* __restrict__ c3, int n3, int* __restrict__ r3,
    int* __restrict__ c4, int n4, int* __restrict__ r4) {
  int* in; int n; int* out;
  switch (blockIdx.x) {
    case 0: in = c0; n = n0; out = r0; break;
    case 1: in = c1; n = n1; out = r1; break;
    case 2: in = c2; n = n2; out = r2; break;
    case 3: in = c3; n = n3; out = r3; break;
    default: in = c4; n = n4; out = r4; break;
  }
  __shared__ int buf[1024];
  __shared__ int carry_s;
  if (threadIdx.x == 0) carry_s = 0;
  __syncthreads();
  for (int base = 0; base < n; base += 1024) {
    int i = base + (int)threadIdx.x;
    int v = (i < n) ? in[i] : 0;
    buf[threadIdx.x] = v;
    __syncthreads();
    int x = v;
    for (int off = 1; off < 1024; off <<= 1) {
      int t = (threadIdx.x >= (unsigned)off) ? buf[threadIdx.x - off] : 0;
      __syncthreads();
      x += t;
      buf[threadIdx.x] = x;
      __syncthreads();
    }
    int carry = carry_s;
    if (i < n) {
      int pref = carry + x - v;
      out[i] = pref;
      in[i] = pref;   // scatter cursor
    }
    __syncthreads();
    if (threadIdx.x == 1023) carry_s = carry + buf[1023];
    __syncthreads();
  }
  if (threadIdx.x == 0) out[n] = carry_s;
}
__global__ __launch_bounds__(256) void k_scatter_all(
    const int* __restrict__ e0, int nE0, const int* __restrict__ e1, int nE1,
    const int* __restrict__ e2, int nE2, const int* __restrict__ cl1, int n0,
    const int* __restrict__ cl2, int n1,
    int* __restrict__ c0, int* __restrict__ c1, int* __restrict__ c2,
    int* __restrict__ c3, int* __restrict__ c4,
    int* __restrict__ s0, int* __restrict__ s1, int* __restrict__ s2,
    int* __restrict__ s3, int* __restrict__ s4) {
  int j = blockIdx.x * 256 + threadIdx.x;
  if (j < nE0) { int p = atomicAdd(&c0[e0[nE0 + j]], 1); s0[p] = e0[j]; return; }
  j -= nE0;
  if (j < nE1) { int p = atomicAdd(&c1[e1[nE1 + j]], 1); s1[p] = e1[j]; return; }
  j -= nE1;
  if (j < nE2) { int p = atomicAdd(&c2[e2[nE2 + j]], 1); s2[p] = e2[j]; return; }
  j -= nE2;
  if (j < n0) { int p = atomicAdd(&c3[cl1[j]], 1); s3[p] = j; return; }
  j -= n0;
  if (j < n1) { int p = atomicAdd(&c4[cl2[j]], 1); s4[p] = j; }
}

// ============================ mega weight pack (f16 single plane) ============================
__device__ inline void pack_one(int idx, const float* __restrict__ W,
                                const float* __restrict__ u, const float* __restrict__ sW,
                                u16* __restrict__ out, int C, int K1, int K2, int Kpad) {
  int col = idx / Kpad, kp = idx - col * Kpad;
  int ksrc = -1;
  if (kp < K1) ksrc = kp;
  else if (kp >= HALF && kp - HALF < K2) ksrc = K1 + (kp - HALF);
  float v = 0.f;
  if (ksrc >= 0) {
    if (col < 4 * C) {
      int c = col >> 2, h = col & 3;
      v = W[(size_t)ksrc * 4 * C + h * C + c];
    } else if (col < 4 * C + 4) {
      v = u[(size_t)ksrc * 4 + (col - 4 * C)];
    } else if (sW && col < 5 * C + 4) {
      v = sW[(size_t)ksrc * C + (col - 4 * C - 4)];
    }
  }
  out[idx] = f2h(v);
}
#define P01 (704 * 32)
#define PCAT (704 * 320)
#define PO (64 * 160)
#define PS (576 * 160)
__global__ __launch_bounds__(256) void k_pack_all(
    const float* __restrict__ W01, const float* __restrict__ u01, const float* __restrict__ sW01,
    const float* __restrict__ Wc, const float* __restrict__ uc, const float* __restrict__ sWc,
    const float* __restrict__ Wo, const float* __restrict__ uo, const float* __restrict__ sWo,
    const float* __restrict__ Ws, const float* __restrict__ us,
    const float* __restrict__ x,
    u16* __restrict__ Bp01, u16* __restrict__ Bpc0, u16* __restrict__ Bpc1,
    u16* __restrict__ Bpo, u16* __restrict__ Bps_all, u16* __restrict__ xb, int N0) {
  int j = blockIdx.x * 256 + threadIdx.x;
  if (j < P01) { pack_one(j, W01, u01, sW01, Bp01, CC, 4, 0, 32); return; }
  j -= P01;
  if (j < PCAT) { pack_one(j, Wc, uc, sWc, Bpc0, CC, CC, CC, 320); return; }
  j -= PCAT;
  if (j < PCAT) {
    pack_one(j, Wc + (size_t)2 * CC * HH * CC, uc + (size_t)2 * CC * HH,
             sWc + (size_t)2 * CC * CC, Bpc1, CC, CC, CC, 320);
    return;
  }
  j -= PCAT;
  if (j < PO) { pack_one(j, Wo, uo, sWo, Bpo, 1, CC, 0, 160); return; }
  j -= PO;
  if (j < 10 * PS) {
    int layer = j / PS, r = j - layer * PS;
    pack_one(r, Ws + (size_t)layer * CC * 4 * CC, us + (size_t)layer * CC * 4, nullptr,
             Bps_all + (size_t)layer * PS, CC, CC, 0, 160);
    return;
  }
  j -= 10 * PS;
  if (j < N0 * 32) {
    int i = j >> 5, c = j & 31;
    xb[j] = f2h(c < 4 ? x[(size_t)i * 4 + c] : 0.f);
  }
}

// ============================ f16 MFMA GEMM (single pass), split output ============================
//   gc < yEnd            -> Gy f16, row-stride yEnd
//   yEnd <= gc < yEnd+4  -> Gl f32, row-stride 4   (attention logits)
//   yEnd+4 <= gc < +Cs   -> Gs f32, row-stride Cs  (GEMM skip)
__global__ __launch_bounds__(256) void k_gemm_mfma(
    const u16* __restrict__ A1, const u16* __restrict__ A2,
    const int* __restrict__ amap, const u16* __restrict__ Bp,
    u16* __restrict__ Gy, float* __restrict__ Gl, float* __restrict__ Gs,
    int yEnd, int Cs, int N, int Kpad, int lda1) {
  __shared__ __align__(16) u16 As[128 * 32];
  __shared__ __align__(16) u16 Bs[64 * 32];
  const int tid = threadIdx.x;
  const int row0 = blockIdx.y * 128, col0 = blockIdx.x * 64;
  const int w = tid >> 6, lane = tid & 63;
  const int wm = w >> 1, wn = w & 1;
  const int arow = lane & 15, chunk = lane >> 4;
  const int swz = chunk ^ (arow & 3);
  f32x4 acc[4][2];
#pragma unroll
  for (int i = 0; i < 4; ++i)
#pragma unroll
    for (int j = 0; j < 2; ++j) acc[i][j] = (f32x4){0.f, 0.f, 0.f, 0.f};
  const int sar = tid >> 1;
  const int sak = (tid & 1) * 16;
  const int sbc = tid >> 2;
  const int sbk = (tid & 3) * 8;
  for (int k0 = 0; k0 < Kpad; k0 += 32) {
    {
      int gr = row0 + sar;
      short8 v0 = {0, 0, 0, 0, 0, 0, 0, 0}, v1 = v0;
      if (gr < N) {
        int kp0 = k0 + sak;
        const u16* b_;
        int rr, kk, ld;
        if (A2 && kp0 >= HALF) {
          b_ = A2; rr = gr; kk = kp0 - HALF; ld = HALF;
        } else {
          b_ = A1; rr = amap ? amap[gr] : gr; kk = kp0; ld = lda1;
        }
        const u16* p = b_ + (size_t)rr * ld + kk;
        v0 = *(const short8*)(p);
        v1 = *(const short8*)(p + 8);
      }
      int c0 = sak >> 3, sw = sar & 3;
      *(short8*)(As + sar * 32 + ((c0 ^ sw) << 3)) = v0;
      *(short8*)(As + sar * 32 + (((c0 + 1) ^ sw) << 3)) = v1;
    }
    {
      int gc = col0 + sbc;
      short8 v = *(const short8*)(Bp + (size_t)gc * Kpad + k0 + sbk);
      int c = sbk >> 3, sw = sbc & 3;
      *(short8*)(Bs + sbc * 32 + ((c ^ sw) << 3)) = v;
    }
    __syncthreads();
    half8 bf[2], af[4];
#pragma unroll
    for (int ni = 0; ni < 2; ++ni) {
      int col = wn * 32 + ni * 16 + arow;
      bf[ni] = *(const half8*)(Bs + col * 32 + (swz << 3));
    }
#pragma unroll
    for (int mi = 0; mi < 4; ++mi) {
      int r = wm * 64 + mi * 16 + arow;
      af[mi] = *(const half8*)(As + r * 32 + (swz << 3));
    }
#pragma unroll
    for (int mi = 0; mi < 4; ++mi)
#pragma unroll
      for (int ni = 0; ni < 2; ++ni)
        acc[mi][ni] = __builtin_amdgcn_mfma_f32_16x16x32_f16(af[mi], bf[ni], acc[mi][ni], 0, 0, 0);
    __syncthreads();
  }
  const int crow = (lane >> 4) * 4, ccol = lane & 15;
#pragma unroll
  for (int mi = 0; mi < 4; ++mi) {
    int gr0 = row0 + wm * 64 + mi * 16 + crow;
#pragma unroll
    for (int ni = 0; ni < 2; ++ni) {
      int gc = col0 + wn * 32 + ni * 16 + ccol;
#pragma unroll
      for (int j = 0; j < 4; ++j) {
        int gr = gr0 + j;
        if (gr >= N) continue;
        float v = acc[mi][ni][j];
        if (gc < yEnd) Gy[(size_t)gr * yEnd + gc] = f2h(v);
        else if (gc < yEnd + 4) Gl[(size_t)gr * 4 + (gc - yEnd)] = v;
        else if (gc < yEnd + 4 + Cs) Gs[(size_t)gr * Cs + (gc - yEnd - 4)] = v;
      }
    }
  }
}

// ============================ fused FeaSt agg + LN + skip + relu ============================
// Gy f16 (n,560) head-minor; Gl f32 (n,4); distributed softmax + fdot2 inner loop
__global__ __launch_bounds__(256) void k_agg(
    const u16* __restrict__ Gy, const float* __restrict__ Gl,
    const float* __restrict__ cv, const float* __restrict__ bias,
    const float* __restrict__ g, const float* __restrict__ be,
    const u16* __restrict__ skipA,                              // identity skip f16 (or null)
    const float* __restrict__ Gs, const float* __restrict__ sb, // GEMM skip
    const int* __restrict__ rp, const int* __restrict__ sl,
    u16* __restrict__ outA, int n, int relu) {
  int wid = blockIdx.x * 4 + ((int)threadIdx.x >> 6);
  int lane = threadIdx.x & 63;
  if (wid >= n) return;
  float4 la = *(const float4*)(Gl + (size_t)wid * 4);
  float d0 = cv[0] - la.x, d1 = cv[1] - la.y;
  float d2 = cv[2] - la.z, d3 = cv[3] - la.w;
  int eb = rp[wid], ee = rp[wid + 1];
  const int c0 = lane, c1 = lane + 64, c2 = lane + 128;
  const bool h2v = c2 < CC;
  float acc0 = 0.f, acc1 = 0.f, acc2 = 0.f;
  for (int base = eb; base < ee; base += 64) {
    int m = min(ee - base, 64);
    // phase 1: lane j computes softmax weights for edge base+j, packs to 2 x f16x2
    int sreg = 0;
    int q01 = 0, q23 = 0;
    if (lane < m) {
      sreg = sl[base + lane];
      float4 lg = *(const float4*)(Gl + (size_t)sreg * 4);
      float t0 = lg.x + d0, t1 = lg.y + d1, t2 = lg.z + d2, t3 = lg.w + d3;
      float mx = fmaxf(fmaxf(t0, t1), fmaxf(t2, t3));
      float q0 = __expf(t0 - mx), q1 = __expf(t1 - mx);
      float q2 = __expf(t2 - mx), q3 = __expf(t3 - mx);
      float qi = 1.f / (q0 + q1 + q2 + q3);
      q01 = (int)((unsigned)f2h(q0 * qi) | ((unsigned)f2h(q1 * qi) << 16));
      q23 = (int)((unsigned)f2h(q2 * qi) | ((unsigned)f2h(q3 * qi) << 16));
    }
    // phase 2: broadcast edge j's (src, q) to all lanes; gather + dot2
#pragma unroll 2
    for (int j = 0; j < m; ++j) {
      int s = __shfl(sreg, j);
      h2 p01 = u2h2((unsigned)__shfl(q01, j));
      h2 p23 = u2h2((unsigned)__shfl(q23, j));
      const u16* gy = Gy + (size_t)s * 560;
      uint2 y0 = *(const uint2*)(gy + (c0 << 2));
      acc0 = dot2(u2h2(y0.x), p01, acc0);
      acc0 = dot2(u2h2(y0.y), p23, acc0);
      uint2 y1 = *(const uint2*)(gy + (c1 << 2));
      acc1 = dot2(u2h2(y1.x), p01, acc1);
      acc1 = dot2(u2h2(y1.y), p23, acc1);
      if (h2v) {
        uint2 y2 = *(const uint2*)(gy + (c2 << 2));
        acc2 = dot2(u2h2(y2.x), p01, acc2);
        acc2 = dot2(u2h2(y2.y), p23, acc2);
      }
    }
  }
  int cnt = ee - eb;
  float inv = 1.f / (float)(cnt > 1 ? cnt : 1);
  float v0 = acc0 * inv + bias[c0];
  float v1 = acc1 * inv + bias[c1];
  float v2 = h2v ? acc2 * inv + bias[c2] : 0.f;
  if (g) {
    float s1 = v0 + v1 + v2;
    float s2 = v0 * v0 + v1 * v1 + v2 * v2;
#pragma unroll
    for (int off = 32; off > 0; off >>= 1) {
      s1 += __shfl_xor(s1, off);
      s2 += __shfl_xor(s2, off);
    }
    float mu = s1 * (1.0f / CC);
    float var = s2 * (1.0f / CC) - mu * mu;
    float r = rsqrtf(var + 1e-5f);
    v0 = (v0 - mu) * r * g[c0] + be[c0];
    v1 = (v1 - mu) * r * g[c1] + be[c1];
    if (h2v) v2 = (v2 - mu) * r * g[c2] + be[c2];
  }
  if (skipA) {
    const u16* sk = skipA + (size_t)wid * HALF;
    v0 += h2f(sk[c0]);
    v1 += h2f(sk[c1]);
    if (h2v) v2 += h2f(sk[c2]);
  } else {
    const float* gsr = Gs + (size_t)wid * CC;
    v0 += gsr[c0] + sb[c0];
    v1 += gsr[c1] + sb[c1];
    if (h2v) v2 += gsr[c2] + sb[c2];
  }
  if (relu) {
    v0 = fmaxf(v0, 0.f); v1 = fmaxf(v1, 0.f); v2 = fmaxf(v2, 0.f);
  }
  u16* oa = outA + (size_t)wid * HALF;
  oa[c0] = f2h(v0);
  oa[c1] = f2h(v1);
  if (h2v) oa[c2] = f2h(v2);
  else if (c2 < HALF) oa[c2] = 0;
}

// conv06: Gy f16 (n,4) = Y heads; Gl f32 logits; Gs f32 (n,1) skip
__global__ __launch_bounds__(256) void k_out(
    const u16* __restrict__ Gy, const float* __restrict__ Gl,
    const float* __restrict__ cv, const float* __restrict__ bo,
    const float* __restrict__ Gs, const float* __restrict__ sbo,
    const int* __restrict__ rp, const int* __restrict__ sl,
    float* __restrict__ out, int n) {
  int wid = blockIdx.x * 4 + ((int)threadIdx.x >> 6);
  int lane = threadIdx.x & 63;
  if (wid >= n) return;
  float4 la = *(const float4*)(Gl + (size_t)wid * 4);
  float d0 = cv[0] - la.x, d1 = cv[1] - la.y;
  float d2 = cv[2] - la.z, d3 = cv[3] - la.w;
  int eb = rp[wid], ee = rp[wid + 1];
  float part = 0.f;
  for (int e = eb + lane; e < ee; e += 64) {
    int s = sl[e];
    float4 lg = *(const float4*)(Gl + (size_t)s * 4);
    float t0 = lg.x + d0, t1 = lg.y + d1, t2 = lg.z + d2, t3 = lg.w + d3;
    float m = fmaxf(fmaxf(t0, t1), fmaxf(t2, t3));
    float q0 = __expf(t0 - m), q1 = __expf(t1 - m), q2 = __expf(t2 - m), q3 = __expf(t3 - m);
    float qi = 1.f / (q0 + q1 + q2 + q3);
    uint2 y = *(const uint2*)(Gy + (size_t)s * 4);
    h2 y01 = u2h2(y.x), y23 = u2h2(y.y);
    part += (q0 * (float)y01[0] + q1 * (float)y01[1] +
             q2 * (float)y23[0] + q3 * (float)y23[1]) * qi;
  }
#pragma unroll
  for (int off = 32; off > 0; off >>= 1) part += __shfl_xor(part, off);
  if (lane == 0) {
    int cnt = ee - eb;
    out[wid] = part / (float)(cnt > 1 ? cnt : 1) + bo[0] + Gs[wid] + sbo[0];
  }
}

// ============================ pool (f16 in/out) ============================
__global__ __launch_bounds__(256) void k_pool(const u16* __restrict__ inA,
                                              const int* __restrict__ rp,
                                              const int* __restrict__ sl,
                                              u16* __restrict__ outA, int nseg) {
  int wid = blockIdx.x * 4 + ((int)threadIdx.x >> 6);
  int lane = threadIdx.x & 63;
  if (wid >= nseg) return;
  int a = rp[wid], b = rp[wid + 1];
  const int c0 = lane, c1 = lane + 64, c2 = lane + 128;
  const bool h2v = c2 < CC;
  float acc0 = 0.f, acc1 = 0.f, acc2 = 0.f;
  for (int s = a; s < b; ++s) {
    size_t off = (size_t)sl[s] * HALF;
    acc0 += h2f(inA[off + c0]);
    acc1 += h2f(inA[off + c1]);
    if (h2v) acc2 += h2f(inA[off + c2]);
  }
  int cnt = b - a;
  float inv = 1.f / (float)(cnt > 1 ? cnt : 1);
  u16* oa = outA + (size_t)wid * HALF;
  oa[c0] = f2h(acc0 * inv);
  oa[c1] = f2h(acc1 * inv);
  if (h2v) oa[c2] = f2h(acc2 * inv);
  else if (c2 < HALF) oa[c2] = 0;
}

// ============================ host ============================
extern "C" void kernel_launch(void* const* d_in, const int* in_sizes, int n_in,
                              void* d_out, int out_size, void* d_ws, size_t ws_size,
                              hipStream_t stream) {
  (void)n_in; (void)out_size;
  const float* x    = (const float*)d_in[0];
  const int*   e0   = (const int*)d_in[1];
  const int*   e1   = (const int*)d_in[2];
  const int*   e2   = (const int*)d_in[3];
  const int*   cl1  = (const int*)d_in[4];
  const int*   cl2  = (const int*)d_in[5];
  const float* W01  = (const float*)d_in[9];
  const float* u01  = (const float*)d_in[10];
  const float* c01  = (const float*)d_in[11];
  const float* b01  = (const float*)d_in[12];
  const float* sW01 = (const float*)d_in[13];
  const float* sb01 = (const float*)d_in[14];
  const float* g01  = (const float*)d_in[15];
  const float* be01 = (const float*)d_in[16];
  const float* Ws   = (const float*)d_in[17];
  const float* us   = (const float*)d_in[18];
  const float* cs   = (const float*)d_in[19];
  const float* bs   = (const float*)d_in[20];
  const float* gs   = (const float*)d_in[21];
  const float* bes  = (const float*)d_in[22];
  const float* Wc   = (const float*)d_in[23];
  const float* uc   = (const float*)d_in[24];
  const float* cc   = (const float*)d_in[25];
  const float* bc   = (const float*)d_in[26];
  const float* sWc  = (const float*)d_in[27];
  const float* sbc  = (const float*)d_in[28];
  const float* gc   = (const float*)d_in[29];
  const float* bec  = (const float*)d_in[30];
  const float* Wo   = (const float*)d_in[31];
  const float* uo   = (const float*)d_in[32];
  const float* co   = (const float*)d_in[33];
  const float* bo   = (const float*)d_in[34];
  const float* sWo  = (const float*)d_in[35];
  const float* sbo  = (const float*)d_in[36];

  const int N0 = in_sizes[0] / 4;
  const int nE0 = in_sizes[1] / 2;
  const int nE1 = in_sizes[2] / 2;
  const int nE2 = in_sizes[3] / 2;
  const int N1 = 5000, N2 = 1250;

  // ---- workspace layout ----
  float* fp = (float*)d_ws;
  auto alloc_f = [&](size_t n) { n = (n + 15) & ~(size_t)15; float* p = fp; fp += n; return p; };
  auto alloc_h = [&](size_t n) { return (u16*)alloc_f((n + 1) / 2); };
  u16*   Gy = alloc_h((size_t)N0 * 560);
  float* Gl = alloc_f((size_t)N0 * 4);
  float* Gs = alloc_f((size_t)N0 * CC);
  u16* a0A = alloc_h((size_t)N0 * HALF);
  u16* a0B = alloc_h((size_t)N0 * HALF);
  u16* a1A = alloc_h((size_t)N1 * HALF);
  u16* a1B = alloc_h((size_t)N1 * HALF);
  u16* a2A = alloc_h((size_t)N2 * HALF);
  u16* a2B = alloc_h((size_t)N2 * HALF);
  u16* xb  = alloc_h((size_t)N0 * 32);
  u16* Bp01 = alloc_h(P01);
  u16* Bpc0 = alloc_h(PCAT);
  u16* Bpc1 = alloc_h(PCAT);
  u16* Bpo  = alloc_h(PO);
  u16* Bps_all = alloc_h((size_t)10 * PS);
  u16* Bps[10];
  for (int i = 0; i < 10; ++i) Bps[i] = Bps_all + (size_t)i * PS;
  int* ipb = (int*)fp;
  auto alloc_i = [&](size_t n) { int* p = ipb; ipb += n; return p; };
  int* rp0  = alloc_i(N0 + 1);
  int* sl0  = alloc_i(nE0);
  int* rp1  = alloc_i(N1 + 1);
  int* sl1  = alloc_i(nE1);
  int* rp2  = alloc_i(N2 + 1);
  int* sl2  = alloc_i(nE2);
  int* rpc1 = alloc_i(N1 + 1);
  int* slc1 = alloc_i(N0);
  int* rpc2 = alloc_i(N2 + 1);
  int* slc2 = alloc_i(N1);
  int* cur0 = alloc_i(N0);
  int* cur1 = alloc_i(N1);
  int* cur2 = alloc_i(N2);
  int* cur3 = alloc_i(N1);
  int* cur4 = alloc_i(N2);
  const int curTot = N0 + N1 + N2 + N1 + N2;
  if ((size_t)((char*)ipb - (char*)d_ws) > ws_size) return;

  auto cdiv = [](int a, int b) { return (a + b - 1) / b; };

  // ---- CSR build: 4 launches ----
  k_zero_i32<<<cdiv(curTot, 256), 256, 0, stream>>>(cur0, curTot);
  {
    int tot = nE0 + nE1 + nE2 + N0 + N1;
    k_hist_all<<<cdiv(tot, 256), 256, 0, stream>>>(e0, nE0, e1, nE1, e2, nE2, cl1, N0, cl2, N1,
                                                   cur0, cur1, cur2, cur3, cur4);
    k_exscan5<<<5, 1024, 0, stream>>>(cur0, N0, rp0, cur1, N1, rp1, cur2, N2, rp2,
                                      cur3, N1, rpc1, cur4, N2, rpc2);
    k_scatter_all<<<cdiv(tot, 256), 256, 0, stream>>>(e0, nE0, e1, nE1, e2, nE2, cl1, N0, cl2, N1,
                                                      cur0, cur1, cur2, cur3, cur4,
                                                      sl0, sl1, sl2, slc1, slc2);
  }
  // ---- mega pack ----
  {
    int tot = P01 + 2 * PCAT + PO + 10 * PS + N0 * 32;
    k_pack_all<<<cdiv(tot, 256), 256, 0, stream>>>(W01, u01, sW01, Wc, uc, sWc, Wo, uo, sWo,
                                                   Ws, us, x, Bp01, Bpc0, Bpc1, Bpo,
                                                   Bps_all, xb, N0);
  }

  // conv driver
  auto do_conv = [&](const u16* A1, const u16* A2, const int* amap, int Kpad, int lda1,
                     const u16* Bp, int Mld, bool hasSkip, int n, const int* rp, const int* sl,
                     const float* cp, const float* bp, const float* gp, const float* bep,
                     const u16* skipA, const float* sbp, u16* outA) {
    dim3 grid(Mld / 64, cdiv(n, 128));
    k_gemm_mfma<<<grid, 256, 0, stream>>>(A1, A2, amap, Bp, Gy, Gl, Gs,
                                          560, hasSkip ? CC : 0, n, Kpad, lda1);
    k_agg<<<cdiv(n, 4), 256, 0, stream>>>(Gy, Gl, cp, bp, gp, bep, skipA, Gs, sbp,
                                          rp, sl, outA, n, 1);
  };

  auto ci  = [&](int i) { return cs + (size_t)i * HH; };
  auto bi  = [&](int i) { return bs + (size_t)i * CC; };
  auto gi  = [&](int i) { return gs + (size_t)i * CC; };
  auto bei = [&](int i) { return bes + (size_t)i * CC; };

  // conv01: K=4 (padded 32), GEMM skip
  do_conv(xb, nullptr, nullptr, 32, 32, Bp01, 704, true, N0, rp0, sl0,
          c01, b01, g01, be01, nullptr, sb01, a0A);
  // conv02 (identity skip) -> copy0 = a0B
  do_conv(a0A, nullptr, nullptr, 160, HALF, Bps[0], 576, false, N0, rp0, sl0,
          ci(0), bi(0), gi(0), bei(0), a0A, nullptr, a0B);
  // pool1
  k_pool<<<cdiv(N1, 4), 256, 0, stream>>>(a0B, rpc1, slc1, a1A, N1);
  // conv11, conv12 (copy1 = a1A after conv12)
  do_conv(a1A, nullptr, nullptr, 160, HALF, Bps[1], 576, false, N1, rp1, sl1,
          ci(1), bi(1), gi(1), bei(1), a1A, nullptr, a1B);
  do_conv(a1B, nullptr, nullptr, 160, HALF, Bps[2], 576, false, N1, rp1, sl1,
          ci(2), bi(2), gi(2), bei(2), a1B, nullptr, a1A);
  // pool2
  k_pool<<<cdiv(N2, 4), 256, 0, stream>>>(a1A, rpc2, slc2, a2A, N2);
  // conv21, conv22
  do_conv(a2A, nullptr, nullptr, 160, HALF, Bps[3], 576, false, N2, rp2, sl2,
          ci(3), bi(3), gi(3), bei(3), a2A, nullptr, a2B);
  do_conv(a2B, nullptr, nullptr, 160, HALF, Bps[4], 576, false, N2, rp2, sl2,
          ci(4), bi(4), gi(4), bei(4), a2B, nullptr, a2A);
  // conv13 on [unpool2(a2A) | a1A], GEMM skip
  do_conv(a2A, a1A, cl2, 320, HALF, Bpc0, 704, true, N1, rp1, sl1,
          cc, bc, gc, bec, nullptr, sbc, a1B);
  // conv14, conv15, conv16
  do_conv(a1B, nullptr, nullptr, 160, HALF, Bps[5], 576, false, N1, rp1, sl1,
          ci(5), bi(5), gi(5), bei(5), a1B, nullptr, a1A);
  do_conv(a1A, nullptr, nullptr, 160, HALF, Bps[6], 576, false, N1, rp1, sl1,
          ci(6), bi(6), gi(6), bei(6), a1A, nullptr, a1B);
  do_conv(a1B, nullptr, nullptr, 160, HALF, Bps[7], 576, false, N1, rp1, sl1,
          ci(7), bi(7), gi(7), bei(7), a1B, nullptr, a1A);
  // conv03 on [unpool1(a1A) | a0B], GEMM skip
  do_conv(a1A, a0B, cl1, 320, HALF, Bpc1, 704, true, N0, rp0, sl0,
          cc + HH, bc + CC, gc + CC, bec + CC, nullptr, sbc + CC, a0A);
  // conv04, conv05
  do_conv(a0A, nullptr, nullptr, 160, HALF, Bps[8], 576, false, N0, rp0, sl0,
          ci(8), bi(8), gi(8), bei(8), a0A, nullptr, a0B);
  do_conv(a0B, nullptr, nullptr, 160, HALF, Bps[9], 576, false, N0, rp0, sl0,
          ci(9), bi(9), gi(9), bei(9), a0B, nullptr, a0A);
  // conv06: 140 -> 1   (Gy stride 4, logits in Gl, skip in Gs col 0)
  {
    dim3 grid(1, cdiv(N0, 128));
    k_gemm_mfma<<<grid, 256, 0, stream>>>(a0A, nullptr, nullptr, Bpo, Gy, Gl, Gs,
                                          4, 1, N0, 160, HALF);
    k_out<<<cdiv(N0, 4), 256, 0, stream>>>(Gy, Gl, co, bo, Gs, sbo, rp0, sl0, (float*)d_out, N0);
  }
}

// Round 8
// 673.078 us; speedup vs baseline: 3.3375x; 1.0596x over previous
//
#include <hip/hip_runtime.h>
#include <math.h>

#define HH 4
#define CC 140
#define HALF 160   // padded K of one concat half / one plain input

typedef __attribute__((ext_vector_type(8))) short short8;
typedef __attribute__((ext_vector_type(8))) _Float16 half8;
typedef __attribute__((ext_vector_type(4))) float f32x4;
typedef __attribute__((ext_vector_type(2))) _Float16 h2;
typedef unsigned short u16;

__device__ inline u16 f2h(float x) {
  union { _Float16 h; u16 u; } v; v.h = (_Float16)x; return v.u;
}
__device__ inline float h2f(u16 u) {
  union { _Float16 h; u16 u; } v; v.u = u; return (float)v.h;
}
__device__ inline h2 u2h2(unsigned u) {
  union { unsigned u; h2 h; } v; v.u = u; return v.h;
}
__device__ inline float dot2(h2 a, h2 b, float c) {
#if __has_builtin(__builtin_amdgcn_fdot2)
  return __builtin_amdgcn_fdot2(a, b, c, false);
#else
  return c + (float)a[0] * (float)b[0] + (float)a[1] * (float)b[1];
#endif
}

// ============================ fused CSR build (4 launches) ============================
__global__ __launch_bounds__(256) void k_zero_i32(int* __restrict__ p, int n) {
  int i = blockIdx.x * 256 + threadIdx.x;
  if (i < n) p[i] = 0;
}
__global__ __launch_bounds__(256) void k_hist_all(
    const int* __restrict__ e0, int nE0, const int* __restrict__ e1, int nE1,
    const int* __restrict__ e2, int nE2, const int* __restrict__ cl1, int n0,
    const int* __restrict__ cl2, int n1,
    int* __restrict__ c0, int* __restrict__ c1, int* __restrict__ c2,
    int* __restrict__ c3, int* __restrict__ c4) {
  int j = blockIdx.x * 256 + threadIdx.x;
  if (j < nE0) { atomicAdd(&c0[e0[nE0 + j]], 1); return; }
  j -= nE0;
  if (j < nE1) { atomicAdd(&c1[e1[nE1 + j]], 1); return; }
  j -= nE1;
  if (j < nE2) { atomicAdd(&c2[e2[nE2 + j]], 1); return; }
  j -= nE2;
  if (j < n0) { atomicAdd(&c3[cl1[j]], 1); return; }
  j -= n0;
  if (j < n1) { atomicAdd(&c4[cl2[j]], 1); }
}
__global__ __launch_bounds__(1024) void k_exscan5(
    int* __restrict__ c0, int n0, int* __restrict__ r0,
    int* __restrict__ c1, int n1, int* __restrict__ r1,
    int* __restrict__ c2, int n2, int* __restrict__ r2,
    int* __restrict__ c3, int n3, int* __restrict__ r3,
    int* __restrict__ c4, int n4, int* __restrict__ r4) {
  int* in; int n; int* out;
  switch (blockIdx.x) {
    case 0: in = c0; n = n0; out = r0; break;
    case 1: in = c1; n = n1; out = r1; break;
    case 2: in = c2; n = n2; out = r2; break;
    case 3: in = c3; n = n3; out = r3; break;
    default: in = c4; n = n4; out = r4; break;
  }
  __shared__ int buf[1024];
  __shared__ int carry_s;
  if (threadIdx.x == 0) carry_s = 0;
  __syncthreads();
  for (int base = 0; base < n; base += 1024) {
    int i = base + (int)threadIdx.x;
    int v = (i < n) ? in[i] : 0;
    buf[threadIdx.x] = v;
    __syncthreads();
    int x = v;
    for (int off = 1; off < 1024; off <<= 1) {
      int t = (threadIdx.x >= (unsigned)off) ? buf[threadIdx.x - off] : 0;
      __syncthreads();
      x += t;
      buf[threadIdx.x] = x;
      __syncthreads();
    }
    int carry = carry_s;
    if (i < n) {
      int pref = carry + x - v;
      out[i] = pref;
      in[i] = pref;
    }
    __syncthreads();
    if (threadIdx.x == 1023) carry_s = carry + buf[1023];
    __syncthreads();
  }
  if (threadIdx.x == 0) out[n] = carry_s;
}
__global__ __launch_bounds__(256) void k_scatter_all(
    const int* __restrict__ e0, int nE0, const int* __restrict__ e1, int nE1,
    const int* __restrict__ e2, int nE2, const int* __restrict__ cl1, int n0,
    const int* __restrict__ cl2, int n1,
    int* __restrict__ c0, int* __restrict__ c1, int* __restrict__ c2,
    int* __restrict__ c3, int* __restrict__ c4,
    int* __restrict__ s0, int* __restrict__ s1, int* __restrict__ s2,
    int* __restrict__ s3, int* __restrict__ s4) {
  int j = blockIdx.x * 256 + threadIdx.x;
  if (j < nE0) { int p = atomicAdd(&c0[e0[nE0 + j]], 1); s0[p] = e0[j]; return; }
  j -= nE0;
  if (j < nE1) { int p = atomicAdd(&c1[e1[nE1 + j]], 1); s1[p] = e1[j]; return; }
  j -= nE1;
  if (j < nE2) { int p = atomicAdd(&c2[e2[nE2 + j]], 1); s2[p] = e2[j]; return; }
  j -= nE2;
  if (j < n0) { int p = atomicAdd(&c3[cl1[j]], 1); s3[p] = j; return; }
  j -= n0;
  if (j < n1) { int p = atomicAdd(&c4[cl2[j]], 1); s4[p] = j; }
}

// ============================ mega weight pack (f16 single plane) ============================
__device__ inline void pack_one(int idx, const float* __restrict__ W,
                                const float* __restrict__ u, const float* __restrict__ sW,
                                u16* __restrict__ out, int C, int K1, int K2, int Kpad) {
  int col = idx / Kpad, kp = idx - col * Kpad;
  int ksrc = -1;
  if (kp < K1) ksrc = kp;
  else if (kp >= HALF && kp - HALF < K2) ksrc = K1 + (kp - HALF);
  float v = 0.f;
  if (ksrc >= 0) {
    if (col < 4 * C) {
      int c = col >> 2, h = col & 3;
      v = W[(size_t)ksrc * 4 * C + h * C + c];
    } else if (col < 4 * C + 4) {
      v = u[(size_t)ksrc * 4 + (col - 4 * C)];
    } else if (sW && col < 5 * C + 4) {
      v = sW[(size_t)ksrc * C + (col - 4 * C - 4)];
    }
  }
  out[idx] = f2h(v);
}
#define P01 (704 * 32)
#define PCAT (704 * 320)
#define PO (64 * 160)
#define PS (576 * 160)
__global__ __launch_bounds__(256) void k_pack_all(
    const float* __restrict__ W01, const float* __restrict__ u01, const float* __restrict__ sW01,
    const float* __restrict__ Wc, const float* __restrict__ uc, const float* __restrict__ sWc,
    const float* __restrict__ Wo, const float* __restrict__ uo, const float* __restrict__ sWo,
    const float* __restrict__ Ws, const float* __restrict__ us,
    const float* __restrict__ x,
    u16* __restrict__ Bp01, u16* __restrict__ Bpc0, u16* __restrict__ Bpc1,
    u16* __restrict__ Bpo, u16* __restrict__ Bps_all, u16* __restrict__ xb, int N0) {
  int j = blockIdx.x * 256 + threadIdx.x;
  if (j < P01) { pack_one(j, W01, u01, sW01, Bp01, CC, 4, 0, 32); return; }
  j -= P01;
  if (j < PCAT) { pack_one(j, Wc, uc, sWc, Bpc0, CC, CC, CC, 320); return; }
  j -= PCAT;
  if (j < PCAT) {
    pack_one(j, Wc + (size_t)2 * CC * HH * CC, uc + (size_t)2 * CC * HH,
             sWc + (size_t)2 * CC * CC, Bpc1, CC, CC, CC, 320);
    return;
  }
  j -= PCAT;
  if (j < PO) { pack_one(j, Wo, uo, sWo, Bpo, 1, CC, 0, 160); return; }
  j -= PO;
  if (j < 10 * PS) {
    int layer = j / PS, r = j - layer * PS;
    pack_one(r, Ws + (size_t)layer * CC * 4 * CC, us + (size_t)layer * CC * 4, nullptr,
             Bps_all + (size_t)layer * PS, CC, CC, 0, 160);
    return;
  }
  j -= 10 * PS;
  if (j < N0 * 32) {
    int i = j >> 5, c = j & 31;
    xb[j] = f2h(c < 4 ? x[(size_t)i * 4 + c] : 0.f);
  }
}

// ============================ f16 MFMA GEMM (single pass), split output ============================
__global__ __launch_bounds__(256) void k_gemm_mfma(
    const u16* __restrict__ A1, const u16* __restrict__ A2,
    const int* __restrict__ amap, const u16* __restrict__ Bp,
    u16* __restrict__ Gy, float* __restrict__ Gl, float* __restrict__ Gs,
    int yEnd, int Cs, int N, int Kpad, int lda1) {
  __shared__ __align__(16) u16 As[128 * 32];
  __shared__ __align__(16) u16 Bs[64 * 32];
  const int tid = threadIdx.x;
  const int row0 = blockIdx.y * 128, col0 = blockIdx.x * 64;
  const int w = tid >> 6, lane = tid & 63;
  const int wm = w >> 1, wn = w & 1;
  const int arow = lane & 15, chunk = lane >> 4;
  const int swz = chunk ^ (arow & 3);
  f32x4 acc[4][2];
#pragma unroll
  for (int i = 0; i < 4; ++i)
#pragma unroll
    for (int j = 0; j < 2; ++j) acc[i][j] = (f32x4){0.f, 0.f, 0.f, 0.f};
  const int sar = tid >> 1;
  const int sak = (tid & 1) * 16;
  const int sbc = tid >> 2;
  const int sbk = (tid & 3) * 8;
  for (int k0 = 0; k0 < Kpad; k0 += 32) {
    {
      int gr = row0 + sar;
      short8 v0 = {0, 0, 0, 0, 0, 0, 0, 0}, v1 = v0;
      if (gr < N) {
        int kp0 = k0 + sak;
        const u16* b_;
        int rr, kk, ld;
        if (A2 && kp0 >= HALF) {
          b_ = A2; rr = gr; kk = kp0 - HALF; ld = HALF;
        } else {
          b_ = A1; rr = amap ? amap[gr] : gr; kk = kp0; ld = lda1;
        }
        const u16* p = b_ + (size_t)rr * ld + kk;
        v0 = *(const short8*)(p);
        v1 = *(const short8*)(p + 8);
      }
      int c0 = sak >> 3, sw = sar & 3;
      *(short8*)(As + sar * 32 + ((c0 ^ sw) << 3)) = v0;
      *(short8*)(As + sar * 32 + (((c0 + 1) ^ sw) << 3)) = v1;
    }
    {
      int gc = col0 + sbc;
      short8 v = *(const short8*)(Bp + (size_t)gc * Kpad + k0 + sbk);
      int c = sbk >> 3, sw = sbc & 3;
      *(short8*)(Bs + sbc * 32 + ((c ^ sw) << 3)) = v;
    }
    __syncthreads();
    half8 bf[2], af[4];
#pragma unroll
    for (int ni = 0; ni < 2; ++ni) {
      int col = wn * 32 + ni * 16 + arow;
      bf[ni] = *(const half8*)(Bs + col * 32 + (swz << 3));
    }
#pragma unroll
    for (int mi = 0; mi < 4; ++mi) {
      int r = wm * 64 + mi * 16 + arow;
      af[mi] = *(const half8*)(As + r * 32 + (swz << 3));
    }
#pragma unroll
    for (int mi = 0; mi < 4; ++mi)
#pragma unroll
      for (int ni = 0; ni < 2; ++ni)
        acc[mi][ni] = __builtin_amdgcn_mfma_f32_16x16x32_f16(af[mi], bf[ni], acc[mi][ni], 0, 0, 0);
    __syncthreads();
  }
  const int crow = (lane >> 4) * 4, ccol = lane & 15;
#pragma unroll
  for (int mi = 0; mi < 4; ++mi) {
    int gr0 = row0 + wm * 64 + mi * 16 + crow;
#pragma unroll
    for (int ni = 0; ni < 2; ++ni) {
      int gc = col0 + wn * 32 + ni * 16 + ccol;
#pragma unroll
      for (int j = 0; j < 4; ++j) {
        int gr = gr0 + j;
        if (gr >= N) continue;
        float v = acc[mi][ni][j];
        if (gc < yEnd) Gy[(size_t)gr * yEnd + gc] = f2h(v);
        else if (gc < yEnd + 4) Gl[(size_t)gr * 4 + (gc - yEnd)] = v;
        else if (gc < yEnd + 4 + Cs) Gs[(size_t)gr * Cs + (gc - yEnd - 4)] = v;
      }
    }
  }
}

// ============================ fused FeaSt agg + LN + skip + relu ============================
// Gy f16 (n,560) head-minor; Gl f32 (n,4); distributed softmax; batched (MLP=12) gather + fdot2
__global__ __launch_bounds__(256) void k_agg(
    const u16* __restrict__ Gy, const float* __restrict__ Gl,
    const float* __restrict__ cv, const float* __restrict__ bias,
    const float* __restrict__ g, const float* __restrict__ be,
    const u16* __restrict__ skipA,
    const float* __restrict__ Gs, const float* __restrict__ sb,
    const int* __restrict__ rp, const int* __restrict__ sl,
    u16* __restrict__ outA, int n, int relu) {
  int wid = blockIdx.x * 4 + ((int)threadIdx.x >> 6);
  int lane = threadIdx.x & 63;
  if (wid >= n) return;
  float4 la = *(const float4*)(Gl + (size_t)wid * 4);
  float d0 = cv[0] - la.x, d1 = cv[1] - la.y;
  float d2 = cv[2] - la.z, d3 = cv[3] - la.w;
  int eb = rp[wid], ee = rp[wid + 1];
  const int c0 = lane, c1 = lane + 64, c2 = lane + 128;
  const bool h2v = c2 < CC;
  float acc0 = 0.f, acc1 = 0.f, acc2 = 0.f;
  for (int base = eb; base < ee; base += 64) {
    int m = min(ee - base, 64);
    // phase 1: lane j computes softmax weights for edge base+j
    int sreg = 0;
    int q01 = 0, q23 = 0;
    if (lane < m) {
      sreg = sl[base + lane];
      float4 lg = *(const float4*)(Gl + (size_t)sreg * 4);
      float t0 = lg.x + d0, t1 = lg.y + d1, t2 = lg.z + d2, t3 = lg.w + d3;
      float mx = fmaxf(fmaxf(t0, t1), fmaxf(t2, t3));
      float q0 = __expf(t0 - mx), q1 = __expf(t1 - mx);
      float q2 = __expf(t2 - mx), q3 = __expf(t3 - mx);
      float qi = 1.f / (q0 + q1 + q2 + q3);
      q01 = (int)((unsigned)f2h(q0 * qi) | ((unsigned)f2h(q1 * qi) << 16));
      q23 = (int)((unsigned)f2h(q2 * qi) | ((unsigned)f2h(q3 * qi) << 16));
    }
    // phase 2: batches of 4 edges — issue all 12 gathers, then 24 dots
    for (int jb = 0; jb < m; jb += 4) {
      uint2 Y0[4], Y1[4], Y2[4];
      unsigned P01v[4], P23v[4];
#pragma unroll
      for (int t = 0; t < 4; ++t) {
        int j = jb + t;  // <= 63 always
        int s = __shfl(sreg, j);
        unsigned p01 = (unsigned)__shfl(q01, j);
        unsigned p23 = (unsigned)__shfl(q23, j);
        bool v = (j < m);
        P01v[t] = v ? p01 : 0u;
        P23v[t] = v ? p23 : 0u;
        if (v) {
          const u16* gy = Gy + (size_t)s * 560;
          Y0[t] = *(const uint2*)(gy + (c0 << 2));
          Y1[t] = *(const uint2*)(gy + (c1 << 2));
          Y2[t] = h2v ? *(const uint2*)(gy + (c2 << 2)) : make_uint2(0u, 0u);
        } else {
          Y0[t] = make_uint2(0u, 0u);
          Y1[t] = make_uint2(0u, 0u);
          Y2[t] = make_uint2(0u, 0u);
        }
      }
#pragma unroll
      for (int t = 0; t < 4; ++t) {
        h2 p01 = u2h2(P01v[t]), p23 = u2h2(P23v[t]);
        acc0 = dot2(u2h2(Y0[t].x), p01, acc0);
        acc0 = dot2(u2h2(Y0[t].y), p23, acc0);
        acc1 = dot2(u2h2(Y1[t].x), p01, acc1);
        acc1 = dot2(u2h2(Y1[t].y), p23, acc1);
        acc2 = dot2(u2h2(Y2[t].x), p01, acc2);
        acc2 = dot2(u2h2(Y2[t].y), p23, acc2);
      }
    }
  }
  int cnt = ee - eb;
  float inv = 1.f / (float)(cnt > 1 ? cnt : 1);
  float v0 = acc0 * inv + bias[c0];
  float v1 = acc1 * inv + bias[c1];
  float v2 = h2v ? acc2 * inv + bias[c2] : 0.f;
  if (g) {
    float s1 = v0 + v1 + v2;
    float s2 = v0 * v0 + v1 * v1 + v2 * v2;
#pragma unroll
    for (int off = 32; off > 0; off >>= 1) {
      s1 += __shfl_xor(s1, off);
      s2 += __shfl_xor(s2, off);
    }
    float mu = s1 * (1.0f / CC);
    float var = s2 * (1.0f / CC) - mu * mu;
    float r = rsqrtf(var + 1e-5f);
    v0 = (v0 - mu) * r * g[c0] + be[c0];
    v1 = (v1 - mu) * r * g[c1] + be[c1];
    if (h2v) v2 = (v2 - mu) * r * g[c2] + be[c2];
  }
  if (skipA) {
    const u16* sk = skipA + (size_t)wid * HALF;
    v0 += h2f(sk[c0]);
    v1 += h2f(sk[c1]);
    if (h2v) v2 += h2f(sk[c2]);
  } else {
    const float* gsr = Gs + (size_t)wid * CC;
    v0 += gsr[c0] + sb[c0];
    v1 += gsr[c1] + sb[c1];
    if (h2v) v2 += gsr[c2] + sb[c2];
  }
  if (relu) {
    v0 = fmaxf(v0, 0.f); v1 = fmaxf(v1, 0.f); v2 = fmaxf(v2, 0.f);
  }
  u16* oa = outA + (size_t)wid * HALF;
  oa[c0] = f2h(v0);
  oa[c1] = f2h(v1);
  if (h2v) oa[c2] = f2h(v2);
  else if (c2 < HALF) oa[c2] = 0;
}

// conv06
__global__ __launch_bounds__(256) void k_out(
    const u16* __restrict__ Gy, const float* __restrict__ Gl,
    const float* __restrict__ cv, const float* __restrict__ bo,
    const float* __restrict__ Gs, const float* __restrict__ sbo,
    const int* __restrict__ rp, const int* __restrict__ sl,
    float* __restrict__ out, int n) {
  int wid = blockIdx.x * 4 + ((int)threadIdx.x >> 6);
  int lane = threadIdx.x & 63;
  if (wid >= n) return;
  float4 la = *(const float4*)(Gl + (size_t)wid * 4);
  float d0 = cv[0] - la.x, d1 = cv[1] - la.y;
  float d2 = cv[2] - la.z, d3 = cv[3] - la.w;
  int eb = rp[wid], ee = rp[wid + 1];
  float part = 0.f;
  for (int e = eb + lane; e < ee; e += 64) {
    int s = sl[e];
    float4 lg = *(const float4*)(Gl + (size_t)s * 4);
    float t0 = lg.x + d0, t1 = lg.y + d1, t2 = lg.z + d2, t3 = lg.w + d3;
    float m = fmaxf(fmaxf(t0, t1), fmaxf(t2, t3));
    float q0 = __expf(t0 - m), q1 = __expf(t1 - m), q2 = __expf(t2 - m), q3 = __expf(t3 - m);
    float qi = 1.f / (q0 + q1 + q2 + q3);
    uint2 y = *(const uint2*)(Gy + (size_t)s * 4);
    h2 y01 = u2h2(y.x), y23 = u2h2(y.y);
    part += (q0 * (float)y01[0] + q1 * (float)y01[1] +
             q2 * (float)y23[0] + q3 * (float)y23[1]) * qi;
  }
#pragma unroll
  for (int off = 32; off > 0; off >>= 1) part += __shfl_xor(part, off);
  if (lane == 0) {
    int cnt = ee - eb;
    out[wid] = part / (float)(cnt > 1 ? cnt : 1) + bo[0] + Gs[wid] + sbo[0];
  }
}

// ============================ pool (f16 in/out) ============================
__global__ __launch_bounds__(256) void k_pool(const u16* __restrict__ inA,
                                              const int* __restrict__ rp,
                                              const int* __restrict__ sl,
                                              u16* __restrict__ outA, int nseg) {
  int wid = blockIdx.x * 4 + ((int)threadIdx.x >> 6);
  int lane = threadIdx.x & 63;
  if (wid >= nseg) return;
  int a = rp[wid], b = rp[wid + 1];
  const int c0 = lane, c1 = lane + 64, c2 = lane + 128;
  const bool h2v = c2 < CC;
  float acc0 = 0.f, acc1 = 0.f, acc2 = 0.f;
  for (int s = a; s < b; ++s) {
    size_t off = (size_t)sl[s] * HALF;
    acc0 += h2f(inA[off + c0]);
    acc1 += h2f(inA[off + c1]);
    if (h2v) acc2 += h2f(inA[off + c2]);
  }
  int cnt = b - a;
  float inv = 1.f / (float)(cnt > 1 ? cnt : 1);
  u16* oa = outA + (size_t)wid * HALF;
  oa[c0] = f2h(acc0 * inv);
  oa[c1] = f2h(acc1 * inv);
  if (h2v) oa[c2] = f2h(acc2 * inv);
  else if (c2 < HALF) oa[c2] = 0;
}

// ============================ host ============================
extern "C" void kernel_launch(void* const* d_in, const int* in_sizes, int n_in,
                              void* d_out, int out_size, void* d_ws, size_t ws_size,
                              hipStream_t stream) {
  (void)n_in; (void)out_size;
  const float* x    = (const float*)d_in[0];
  const int*   e0   = (const int*)d_in[1];
  const int*   e1   = (const int*)d_in[2];
  const int*   e2   = (const int*)d_in[3];
  const int*   cl1  = (const int*)d_in[4];
  const int*   cl2  = (const int*)d_in[5];
  const float* W01  = (const float*)d_in[9];
  const float* u01  = (const float*)d_in[10];
  const float* c01  = (const float*)d_in[11];
  const float* b01  = (const float*)d_in[12];
  const float* sW01 = (const float*)d_in[13];
  const float* sb01 = (const float*)d_in[14];
  const float* g01  = (const float*)d_in[15];
  const float* be01 = (const float*)d_in[16];
  const float* Ws   = (const float*)d_in[17];
  const float* us   = (const float*)d_in[18];
  const float* cs   = (const float*)d_in[19];
  const float* bs   = (const float*)d_in[20];
  const float* gs   = (const float*)d_in[21];
  const float* bes  = (const float*)d_in[22];
  const float* Wc   = (const float*)d_in[23];
  const float* uc   = (const float*)d_in[24];
  const float* cc   = (const float*)d_in[25];
  const float* bc   = (const float*)d_in[26];
  const float* sWc  = (const float*)d_in[27];
  const float* sbc  = (const float*)d_in[28];
  const float* gc   = (const float*)d_in[29];
  const float* bec  = (const float*)d_in[30];
  const float* Wo   = (const float*)d_in[31];
  const float* uo   = (const float*)d_in[32];
  const float* co   = (const float*)d_in[33];
  const float* bo   = (const float*)d_in[34];
  const float* sWo  = (const float*)d_in[35];
  const float* sbo  = (const float*)d_in[36];

  const int N0 = in_sizes[0] / 4;
  const int nE0 = in_sizes[1] / 2;
  const int nE1 = in_sizes[2] / 2;
  const int nE2 = in_sizes[3] / 2;
  const int N1 = 5000, N2 = 1250;

  // ---- workspace layout ----
  float* fp = (float*)d_ws;
  auto alloc_f = [&](size_t n) { n = (n + 15) & ~(size_t)15; float* p = fp; fp += n; return p; };
  auto alloc_h = [&](size_t n) { return (u16*)alloc_f((n + 1) / 2); };
  u16*   Gy = alloc_h((size_t)N0 * 560);
  float* Gl = alloc_f((size_t)N0 * 4);
  float* Gs = alloc_f((size_t)N0 * CC);
  u16* a0A = alloc_h((size_t)N0 * HALF);
  u16* a0B = alloc_h((size_t)N0 * HALF);
  u16* a1A = alloc_h((size_t)N1 * HALF);
  u16* a1B = alloc_h((size_t)N1 * HALF);
  u16* a2A = alloc_h((size_t)N2 * HALF);
  u16* a2B = alloc_h((size_t)N2 * HALF);
  u16* xb  = alloc_h((size_t)N0 * 32);
  u16* Bp01 = alloc_h(P01);
  u16* Bpc0 = alloc_h(PCAT);
  u16* Bpc1 = alloc_h(PCAT);
  u16* Bpo  = alloc_h(PO);
  u16* Bps_all = alloc_h((size_t)10 * PS);
  u16* Bps[10];
  for (int i = 0; i < 10; ++i) Bps[i] = Bps_all + (size_t)i * PS;
  int* ipb = (int*)fp;
  auto alloc_i = [&](size_t n) { int* p = ipb; ipb += n; return p; };
  int* rp0  = alloc_i(N0 + 1);
  int* sl0  = alloc_i(nE0);
  int* rp1  = alloc_i(N1 + 1);
  int* sl1  = alloc_i(nE1);
  int* rp2  = alloc_i(N2 + 1);
  int* sl2  = alloc_i(nE2);
  int* rpc1 = alloc_i(N1 + 1);
  int* slc1 = alloc_i(N0);
  int* rpc2 = alloc_i(N2 + 1);
  int* slc2 = alloc_i(N1);
  int* cur0 = alloc_i(N0);
  int* cur1 = alloc_i(N1);
  int* cur2 = alloc_i(N2);
  int* cur3 = alloc_i(N1);
  int* cur4 = alloc_i(N2);
  const int curTot = N0 + N1 + N2 + N1 + N2;
  if ((size_t)((char*)ipb - (char*)d_ws) > ws_size) return;

  auto cdiv = [](int a, int b) { return (a + b - 1) / b; };

  // ---- CSR build: 4 launches ----
  k_zero_i32<<<cdiv(curTot, 256), 256, 0, stream>>>(cur0, curTot);
  {
    int tot = nE0 + nE1 + nE2 + N0 + N1;
    k_hist_all<<<cdiv(tot, 256), 256, 0, stream>>>(e0, nE0, e1, nE1, e2, nE2, cl1, N0, cl2, N1,
                                                   cur0, cur1, cur2, cur3, cur4);
    k_exscan5<<<5, 1024, 0, stream>>>(cur0, N0, rp0, cur1, N1, rp1, cur2, N2, rp2,
                                      cur3, N1, rpc1, cur4, N2, rpc2);
    k_scatter_all<<<cdiv(tot, 256), 256, 0, stream>>>(e0, nE0, e1, nE1, e2, nE2, cl1, N0, cl2, N1,
                                                      cur0, cur1, cur2, cur3, cur4,
                                                      sl0, sl1, sl2, slc1, slc2);
  }
  // ---- mega pack ----
  {
    int tot = P01 + 2 * PCAT + PO + 10 * PS + N0 * 32;
    k_pack_all<<<cdiv(tot, 256), 256, 0, stream>>>(W01, u01, sW01, Wc, uc, sWc, Wo, uo, sWo,
                                                   Ws, us, x, Bp01, Bpc0, Bpc1, Bpo,
                                                   Bps_all, xb, N0);
  }

  // conv driver
  auto do_conv = [&](const u16* A1, const u16* A2, const int* amap, int Kpad, int lda1,
                     const u16* Bp, int Mld, bool hasSkip, int n, const int* rp, const int* sl,
                     const float* cp, const float* bp, const float* gp, const float* bep,
                     const u16* skipA, const float* sbp, u16* outA) {
    dim3 grid(Mld / 64, cdiv(n, 128));
    k_gemm_mfma<<<grid, 256, 0, stream>>>(A1, A2, amap, Bp, Gy, Gl, Gs,
                                          560, hasSkip ? CC : 0, n, Kpad, lda1);
    k_agg<<<cdiv(n, 4), 256, 0, stream>>>(Gy, Gl, cp, bp, gp, bep, skipA, Gs, sbp,
                                          rp, sl, outA, n, 1);
  };

  auto ci  = [&](int i) { return cs + (size_t)i * HH; };
  auto bi  = [&](int i) { return bs + (size_t)i * CC; };
  auto gi  = [&](int i) { return gs + (size_t)i * CC; };
  auto bei = [&](int i) { return bes + (size_t)i * CC; };

  // conv01: K=4 (padded 32), GEMM skip
  do_conv(xb, nullptr, nullptr, 32, 32, Bp01, 704, true, N0, rp0, sl0,
          c01, b01, g01, be01, nullptr, sb01, a0A);
  // conv02 (identity skip) -> copy0 = a0B
  do_conv(a0A, nullptr, nullptr, 160, HALF, Bps[0], 576, false, N0, rp0, sl0,
          ci(0), bi(0), gi(0), bei(0), a0A, nullptr, a0B);
  // pool1
  k_pool<<<cdiv(N1, 4), 256, 0, stream>>>(a0B, rpc1, slc1, a1A, N1);
  // conv11, conv12 (copy1 = a1A after conv12)
  do_conv(a1A, nullptr, nullptr, 160, HALF, Bps[1], 576, false, N1, rp1, sl1,
          ci(1), bi(1), gi(1), bei(1), a1A, nullptr, a1B);
  do_conv(a1B, nullptr, nullptr, 160, HALF, Bps[2], 576, false, N1, rp1, sl1,
          ci(2), bi(2), gi(2), bei(2), a1B, nullptr, a1A);
  // pool2
  k_pool<<<cdiv(N2, 4), 256, 0, stream>>>(a1A, rpc2, slc2, a2A, N2);
  // conv21, conv22
  do_conv(a2A, nullptr, nullptr, 160, HALF, Bps[3], 576, false, N2, rp2, sl2,
          ci(3), bi(3), gi(3), bei(3), a2A, nullptr, a2B);
  do_conv(a2B, nullptr, nullptr, 160, HALF, Bps[4], 576, false, N2, rp2, sl2,
          ci(4), bi(4), gi(4), bei(4), a2B, nullptr, a2A);
  // conv13 on [unpool2(a2A) | a1A], GEMM skip
  do_conv(a2A, a1A, cl2, 320, HALF, Bpc0, 704, true, N1, rp1, sl1,
          cc, bc, gc, bec, nullptr, sbc, a1B);
  // conv14, conv15, conv16
  do_conv(a1B, nullptr, nullptr, 160, HALF, Bps[5], 576, false, N1, rp1, sl1,
          ci(5), bi(5), gi(5), bei(5), a1B, nullptr, a1A);
  do_conv(a1A, nullptr, nullptr, 160, HALF, Bps[6], 576, false, N1, rp1, sl1,
          ci(6), bi(6), gi(6), bei(6), a1A, nullptr, a1B);
  do_conv(a1B, nullptr, nullptr, 160, HALF, Bps[7], 576, false, N1, rp1, sl1,
          ci(7), bi(7), gi(7), bei(7), a1B, nullptr, a1A);
  // conv03 on [unpool1(a1A) | a0B], GEMM skip
  do_conv(a1A, a0B, cl1, 320, HALF, Bpc1, 704, true, N0, rp0, sl0,
          cc + HH, bc + CC, gc + CC, bec + CC, nullptr, sbc + CC, a0A);
  // conv04, conv05
  do_conv(a0A, nullptr, nullptr, 160, HALF, Bps[8], 576, false, N0, rp0, sl0,
          ci(8), bi(8), gi(8), bei(8), a0A, nullptr, a0B);
  do_conv(a0B, nullptr, nullptr, 160, HALF, Bps[9], 576, false, N0, rp0, sl0,
          ci(9), bi(9), gi(9), bei(9), a0B, nullptr, a0A);
  // conv06: 140 -> 1
  {
    dim3 grid(1, cdiv(N0, 128));
    k_gemm_mfma<<<grid, 256, 0, stream>>>(a0A, nullptr, nullptr, Bpo, Gy, Gl, Gs,
                                          4, 1, N0, 160, HALF);
    k_out<<<cdiv(N0, 4), 256, 0, stream>>>(Gy, Gl, co, bo, Gs, sbo, rp0, sl0, (float*)d_out, N0);
  }
}